// Round 2
// baseline (1623.679 us; speedup 1.0000x reference)
//
#include <hip/hip_runtime.h>
#include <hip/hip_bf16.h>

typedef __hip_bfloat16 bf16;

#define NPIX  131072
#define BATCH 2
#define HH    256
#define WW    256
#define CDIM  96
#define C3    288
#define HEADS 2
#define CH    48
#define HIDN  255
#define HWSZ  65536
#define EPSV  1e-5f

__device__ __forceinline__ float b2f(bf16 v) { return __bfloat162float(v); }
__device__ __forceinline__ bf16  f2b(float v) { return __float2bfloat16(v); }

// ---------------- LayerNorm: fp32 in -> bf16 out, one wave per pixel ----------------
__global__ __launch_bounds__(256) void ln_kernel(const float* __restrict__ x,
    const float* __restrict__ gamma, const float* __restrict__ beta,
    bf16* __restrict__ y)
{
  int wave = threadIdx.x >> 6;
  int lane = threadIdx.x & 63;
  long p = (long)blockIdx.x * 4 + wave;
  const float* xp = x + p * CDIM;
  float v0 = xp[lane];
  float v1 = (lane < 32) ? xp[64 + lane] : 0.f;
  float s  = v0 + v1;
  float sq = v0 * v0 + v1 * v1;
  #pragma unroll
  for (int off = 32; off; off >>= 1) {
    s  += __shfl_xor(s, off);
    sq += __shfl_xor(sq, off);
  }
  float mean = s * (1.f / 96.f);
  float var  = sq * (1.f / 96.f) - mean * mean;
  float rstd = rsqrtf(var + EPSV);
  bf16* yp = y + p * CDIM;
  yp[lane] = f2b((v0 - mean) * rstd * gamma[lane] + beta[lane]);
  if (lane < 32)
    yp[64 + lane] = f2b((v1 - mean) * rstd * gamma[64 + lane] + beta[64 + lane]);
}

// ---- Tiled GEMM: out[M,N] = A[M,KA(bf16),lda] * W[KW,N (stride ldw)](f32) (+res) ----
// M = NPIX (multiple of 64). KA multiple of 32 & 8; A rows read unchecked (must be valid
// finite bf16 out to lda? no: out to k0+ak+8 <= KA). W guarded by k<KW && n<N.
template<bool ADD_RES, bool OUT_BF16>
__global__ __launch_bounds__(256) void gemm_kernel(
    const bf16* __restrict__ A, int lda,
    const float* __restrict__ W, int ldw, int N, int KW,
    void* __restrict__ outp, int ldo,
    const float* __restrict__ res, int ldr,
    int KA)
{
  constexpr int BM = 64, BN = 64, BK = 32;
  __shared__ __align__(16) float As[BK][BM + 4];
  __shared__ __align__(16) float Ws[BK][BN + 4];
  const int tid = threadIdx.x;
  const int bm = blockIdx.y * BM;
  const int bn = blockIdx.x * BN;
  const int tm = tid >> 4, tn = tid & 15;
  const int ar = tid >> 2;          // 0..63 row in A tile
  const int ak = (tid & 3) * 8;     // 0,8,16,24
  const int wr = tid >> 4;          // 0..15
  const int wc = (tid & 15) * 4;
  float acc[4][4] = {};
  for (int k0 = 0; k0 < KA; k0 += BK) {
    {
      const uint4 u = *reinterpret_cast<const uint4*>(A + (long)(bm + ar) * lda + k0 + ak);
      As[ak + 0][ar] = __uint_as_float(u.x << 16);
      As[ak + 1][ar] = __uint_as_float(u.x & 0xffff0000u);
      As[ak + 2][ar] = __uint_as_float(u.y << 16);
      As[ak + 3][ar] = __uint_as_float(u.y & 0xffff0000u);
      As[ak + 4][ar] = __uint_as_float(u.z << 16);
      As[ak + 5][ar] = __uint_as_float(u.z & 0xffff0000u);
      As[ak + 6][ar] = __uint_as_float(u.w << 16);
      As[ak + 7][ar] = __uint_as_float(u.w & 0xffff0000u);
    }
    #pragma unroll
    for (int h = 0; h < 2; ++h) {
      int k = k0 + wr + h * 16;
      #pragma unroll
      for (int j = 0; j < 4; ++j) {
        int n = bn + wc + j;
        float v = 0.f;
        if (k < KW && n < N) v = W[(long)k * ldw + n];
        Ws[wr + h * 16][wc + j] = v;
      }
    }
    __syncthreads();
    #pragma unroll
    for (int k = 0; k < BK; ++k) {
      float4 av = *reinterpret_cast<const float4*>(&As[k][tm * 4]);
      float4 bv = *reinterpret_cast<const float4*>(&Ws[k][tn * 4]);
      acc[0][0] += av.x * bv.x; acc[0][1] += av.x * bv.y; acc[0][2] += av.x * bv.z; acc[0][3] += av.x * bv.w;
      acc[1][0] += av.y * bv.x; acc[1][1] += av.y * bv.y; acc[1][2] += av.y * bv.z; acc[1][3] += av.y * bv.w;
      acc[2][0] += av.z * bv.x; acc[2][1] += av.z * bv.y; acc[2][2] += av.z * bv.z; acc[2][3] += av.z * bv.w;
      acc[3][0] += av.w * bv.x; acc[3][1] += av.w * bv.y; acc[3][2] += av.w * bv.z; acc[3][3] += av.w * bv.w;
    }
    __syncthreads();
  }
  #pragma unroll
  for (int i = 0; i < 4; ++i) {
    long row = bm + tm * 4 + i;
    #pragma unroll
    for (int j = 0; j < 4; ++j) {
      int col = bn + tn * 4 + j;
      if (col < N) {
        float v = acc[i][j];
        if (ADD_RES) v += res[row * ldr + col];
        if (OUT_BF16) ((bf16*)outp)[row * ldo + col] = f2b(v);
        else          ((float*)outp)[row * ldo + col] = v;
      }
    }
  }
}

// ---------------- Depthwise 3x3 conv, SAME zero padding, C channels, lda==C ----------------
template<int C>
__global__ __launch_bounds__(256) void dwconv_kernel(const bf16* __restrict__ in,
    const float* __restrict__ kw, bf16* __restrict__ out)
{
  long idx = (long)blockIdx.x * 256 + threadIdx.x;
  if (idx >= (long)NPIX * C) return;
  int  c  = (int)(idx % C);
  long p  = idx / C;
  int  xw = (int)(p % WW);
  int  yh = (int)((p / WW) % HH);
  long bbase = p - xw - (long)yh * WW;   // b*HWSZ
  float acc = 0.f;
  #pragma unroll
  for (int dy = -1; dy <= 1; ++dy) {
    int yy = yh + dy;
    if (yy < 0 || yy >= HH) continue;
    #pragma unroll
    for (int dx = -1; dx <= 1; ++dx) {
      int xx = xw + dx;
      if (xx < 0 || xx >= WW) continue;
      acc += b2f(in[(bbase + (long)yy * WW + xx) * C + c]) * kw[((dy + 1) * 3 + (dx + 1)) * C + c];
    }
  }
  out[idx] = f2b(acc);
}

// ------- Depthwise 3x3 conv on 255 cols stored with stride 256; kw stride 510 -------
// MODE 0: out = gelu_exact(conv)      (x1 half)
// MODE 1: out *= conv  (in-place elementwise multiply of x2-conv into gelu(x1))
template<int MODE>
__global__ __launch_bounds__(256) void dwconv_ffn_kernel(const bf16* __restrict__ in,
    const float* __restrict__ kw, bf16* __restrict__ out)
{
  long idx = (long)blockIdx.x * 256 + threadIdx.x;
  if (idx >= (long)NPIX * HIDN) return;
  int  c  = (int)(idx % HIDN);
  long p  = idx / HIDN;
  int  xw = (int)(p % WW);
  int  yh = (int)((p / WW) % HH);
  long bbase = p - xw - (long)yh * WW;
  float acc = 0.f;
  #pragma unroll
  for (int dy = -1; dy <= 1; ++dy) {
    int yy = yh + dy;
    if (yy < 0 || yy >= HH) continue;
    #pragma unroll
    for (int dx = -1; dx <= 1; ++dx) {
      int xx = xw + dx;
      if (xx < 0 || xx >= WW) continue;
      acc += b2f(in[(bbase + (long)yy * WW + xx) * 256 + c]) * kw[((dy + 1) * 3 + (dx + 1)) * 510 + c];
    }
  }
  long oi = p * 256 + c;
  if (MODE == 0) {
    float g = 0.5f * acc * (1.f + erff(acc * 0.70710678118654752440f));
    out[oi] = f2b(g);
  } else {
    out[oi] = f2b(b2f(out[oi]) * acc);
  }
}

// ---------------- q/k spatial sum-of-squares (for L2 norms) ----------------
__global__ __launch_bounds__(192) void qknorm_kernel(const bf16* __restrict__ qkv,
    float* __restrict__ nq, float* __restrict__ nk)
{
  int col = threadIdx.x;            // 0..191 = q cols 0..95, k cols 96..191
  long row0 = (long)blockIdx.x * 128;
  float s = 0.f;
  for (int r = 0; r < 128; ++r) {
    float v = b2f(qkv[(row0 + r) * C3 + col]);
    s += v * v;
  }
  int b = (int)(row0 >> 16);        // 65536 pixels per batch, no straddle
  if (col < CDIM) atomicAdd(&nq[b * CDIM + col], s);
  else            atomicAdd(&nk[b * CDIM + col - CDIM], s);
}

// ------- Gram matrix G[b,head,c,d] = sum_s q*k (raw, pre-normalization) -------
__global__ __launch_bounds__(256) void gram_kernel(const bf16* __restrict__ qkv,
    float* __restrict__ G)
{
  int bh = blockIdx.x >> 6;         // 0..3 = b*2+head
  int chunk = blockIdx.x & 63;
  int b = bh >> 1, head = bh & 1;
  long row0 = (long)b * HWSZ + (long)chunk * 1024;
  __shared__ float qs[64][CH], ks[64][CH];
  int tid = threadIdx.x;
  int c0 = (tid >> 4) * 3, d0 = (tid & 15) * 3;
  float acc[3][3] = {};
  for (int it = 0; it < 16; ++it) {
    for (int f = tid; f < 64 * CH; f += 256) {
      int pix = f / CH, cc = f % CH;
      long base = (row0 + it * 64 + pix) * C3 + head * CH;
      qs[pix][cc] = b2f(qkv[base + cc]);
      ks[pix][cc] = b2f(qkv[base + CDIM + cc]);
    }
    __syncthreads();
    for (int s = 0; s < 64; ++s) {
      float q0 = qs[s][c0], q1 = qs[s][c0 + 1], q2 = qs[s][c0 + 2];
      float k0 = ks[s][d0], k1 = ks[s][d0 + 1], k2 = ks[s][d0 + 2];
      acc[0][0] += q0 * k0; acc[0][1] += q0 * k1; acc[0][2] += q0 * k2;
      acc[1][0] += q1 * k0; acc[1][1] += q1 * k1; acc[1][2] += q1 * k2;
      acc[2][0] += q2 * k0; acc[2][1] += q2 * k1; acc[2][2] += q2 * k2;
    }
    __syncthreads();
  }
  float* Gp = G + (long)bh * CH * CH;
  #pragma unroll
  for (int i = 0; i < 3; ++i)
    #pragma unroll
    for (int j = 0; j < 3; ++j)
      atomicAdd(&Gp[(c0 + i) * CH + d0 + j], acc[i][j]);
}

// ---------------- softmax over d of G/(|q||k|)*temp ----------------
__global__ __launch_bounds__(64) void softmax_kernel(const float* __restrict__ G,
    const float* __restrict__ nq, const float* __restrict__ nk,
    const float* __restrict__ temp, float* __restrict__ attn)
{
  int r = blockIdx.x;               // 0..191 = (b*2+head)*48 + c
  int lane = threadIdx.x;
  int bh = r / CH, c = r % CH;
  int b = bh >> 1, head = bh & 1;
  float t  = temp[head];
  float qn = sqrtf(nq[b * CDIM + head * CH + c]);
  float val = 0.f, v = -INFINITY;
  if (lane < CH) {
    float kn = sqrtf(nk[b * CDIM + head * CH + lane]);
    val = G[r * CH + lane] / (qn * kn) * t;
    v = val;
  }
  float m = v;
  #pragma unroll
  for (int off = 32; off; off >>= 1) m = fmaxf(m, __shfl_xor(m, off));
  float e = (lane < CH) ? expf(val - m) : 0.f;
  float s = e;
  #pragma unroll
  for (int off = 32; off; off >>= 1) s += __shfl_xor(s, off);
  if (lane < CH) attn[r * CH + lane] = e / s;
}

// ---- o[p,c] = sum_d attn[head(c)][c%48][d] * v[p, head*48+d] ----
__global__ __launch_bounds__(256) void applyattn_kernel(const bf16* __restrict__ qkv,
    const float* __restrict__ attn, bf16* __restrict__ o)
{
  __shared__ float As[2 * CH * CH];   // 4608 f32
  __shared__ bf16  vs[64][CDIM];
  long p0 = (long)blockIdx.x * 64;
  int b = (int)(p0 >> 16);
  int tid = threadIdx.x;
  for (int f = tid; f < 2 * CH * CH; f += 256) As[f] = attn[(long)b * 2 * CH * CH + f];
  for (int f = tid; f < 64 * CDIM; f += 256) {
    int pix = f / CDIM, cc = f % CDIM;
    vs[pix][cc] = qkv[(p0 + pix) * C3 + 2 * CDIM + cc];
  }
  __syncthreads();
  for (int f = tid; f < 64 * CDIM; f += 256) {
    int pix = f / CDIM, cc = f % CDIM;
    int head = cc / CH, hc = cc % CH;
    const float* Ap = As + (head * CH + hc) * CH;
    const bf16* vp = &vs[pix][head * CH];
    float acc = 0.f;
    #pragma unroll
    for (int d = 0; d < CH; ++d) acc += Ap[d] * b2f(vp[d]);
    o[(p0 + pix) * CDIM + cc] = f2b(acc);
  }
}

extern "C" void kernel_launch(void* const* d_in, const int* in_sizes, int n_in,
                              void* d_out, int out_size, void* d_ws, size_t ws_size,
                              hipStream_t stream)
{
  const float* x          = (const float*)d_in[0];
  const float* ln1_g      = (const float*)d_in[1];
  const float* ln1_b      = (const float*)d_in[2];
  const float* ln2_g      = (const float*)d_in[3];
  const float* ln2_b      = (const float*)d_in[4];
  const float* qkv_w      = (const float*)d_in[5];
  const float* qkv_dw     = (const float*)d_in[6];
  const float* temp       = (const float*)d_in[7];
  const float* attn_out_w = (const float*)d_in[8];
  const float* ffn_in_w   = (const float*)d_in[9];
  const float* ffn_dw     = (const float*)d_in[10];
  const float* ffn_out_w  = (const float*)d_in[11];
  float* out = (float*)d_out;

  // workspace layout (peak ~168.1 MB)
  char* ws = (char*)d_ws;
  size_t off = 0;
  auto alloc = [&](size_t bytes) { void* p = ws + off; off += (bytes + 255) & ~(size_t)255; return p; };
  bf16*  BA  = (bf16*)alloc((size_t)NPIX * C3 * 2);    // "A": qkv post-dwconv; later gelu(x1)/gated
  bf16*  BB  = (bf16*)alloc((size_t)NPIX * C3 * 2);    // "B": qkv pre-dwconv; later t1/t2
  bf16*  BC  = (bf16*)alloc((size_t)NPIX * CDIM * 2);  // "C": ln output / o
  float* NQ  = (float*)alloc(BATCH * CDIM * 4);
  float* NK  = (float*)alloc(BATCH * CDIM * 4);
  float* G   = (float*)alloc(BATCH * HEADS * CH * CH * 4);
  float* ATT = (float*)alloc(BATCH * HEADS * CH * CH * 4);
  // NQ, NK, G contiguous (256B-rounded sizes): zero in one memset
  hipMemsetAsync(NQ, 0, (size_t)(768 + 768 + 36864), stream);

  // ---- attention branch ----
  ln_kernel<<<NPIX / 4, 256, 0, stream>>>(x, ln1_g, ln1_b, BC);
  {
    dim3 g((C3 + 63) / 64, NPIX / 64);
    gemm_kernel<false, true><<<g, 256, 0, stream>>>(BC, CDIM, qkv_w, C3, C3, CDIM, BB, C3, nullptr, 0, CDIM);
  }
  dwconv_kernel<C3><<<(int)(((long)NPIX * C3 + 255) / 256), 256, 0, stream>>>(BB, qkv_dw, BA);
  qknorm_kernel<<<1024, 192, 0, stream>>>(BA, NQ, NK);
  gram_kernel<<<256, 256, 0, stream>>>(BA, G);
  softmax_kernel<<<192, 64, 0, stream>>>(G, NQ, NK, temp, ATT);
  applyattn_kernel<<<NPIX / 64, 256, 0, stream>>>(BA, ATT, BC);
  {
    dim3 g((CDIM + 63) / 64, NPIX / 64);
    gemm_kernel<true, false><<<g, 256, 0, stream>>>(BC, CDIM, attn_out_w, CDIM, CDIM, CDIM, out, CDIM, x, CDIM, CDIM);
  }

  // ---- FFN branch (hidden split into two 255-col halves) ----
  ln_kernel<<<NPIX / 4, 256, 0, stream>>>(out, ln2_g, ln2_b, BC);
  {
    dim3 g((HIDN + 63) / 64, NPIX / 64);
    // t1 = y2 @ ffn_in_w[:, 0:255]  -> BB (stride 256)
    gemm_kernel<false, true><<<g, 256, 0, stream>>>(BC, CDIM, ffn_in_w, 2 * HIDN, HIDN, CDIM, BB, 256, nullptr, 0, CDIM);
  }
  dwconv_ffn_kernel<0><<<(int)(((long)NPIX * HIDN + 255) / 256), 256, 0, stream>>>(BB, ffn_dw, BA);
  {
    dim3 g((HIDN + 63) / 64, NPIX / 64);
    // t2 = y2 @ ffn_in_w[:, 255:510] -> BB (stride 256)
    gemm_kernel<false, true><<<g, 256, 0, stream>>>(BC, CDIM, ffn_in_w + HIDN, 2 * HIDN, HIDN, CDIM, BB, 256, nullptr, 0, CDIM);
  }
  dwconv_ffn_kernel<1><<<(int)(((long)NPIX * HIDN + 255) / 256), 256, 0, stream>>>(BB, ffn_dw + HIDN, BA);
  {
    dim3 g((CDIM + 63) / 64, NPIX / 64);
    // out = gated @ ffn_out_w + out   (gated stride 256, col 255 stale-but-finite * W row>=255 -> 0)
    gemm_kernel<true, false><<<g, 256, 0, stream>>>(BA, 256, ffn_out_w, CDIM, CDIM, HIDN, out, CDIM, out, CDIM, 256);
  }
}

// Round 3
// 1264.525 us; speedup vs baseline: 1.2840x; 1.2840x over previous
//
#include <hip/hip_runtime.h>
#include <hip/hip_bf16.h>

typedef __hip_bfloat16 bf16;

#define NPIX  131072
#define BATCH 2
#define HH    256
#define WW    256
#define CDIM  96
#define C3    288
#define HEADS 2
#define CH    48
#define HIDN  255
#define HWSZ  65536
#define EPSV  1e-5f

__device__ __forceinline__ float b2f(bf16 v) { return __bfloat162float(v); }
__device__ __forceinline__ bf16  f2b(float v) { return __float2bfloat16(v); }

// ---------------- LayerNorm: fp32 in -> bf16 out, one wave per pixel ----------------
__global__ __launch_bounds__(256) void ln_kernel(const float* __restrict__ x,
    const float* __restrict__ gamma, const float* __restrict__ beta,
    bf16* __restrict__ y)
{
  int wave = threadIdx.x >> 6;
  int lane = threadIdx.x & 63;
  long p = (long)blockIdx.x * 4 + wave;
  const float* xp = x + p * CDIM;
  float v0 = xp[lane];
  float v1 = (lane < 32) ? xp[64 + lane] : 0.f;
  float s  = v0 + v1;
  float sq = v0 * v0 + v1 * v1;
  #pragma unroll
  for (int off = 32; off; off >>= 1) {
    s  += __shfl_xor(s, off);
    sq += __shfl_xor(sq, off);
  }
  float mean = s * (1.f / 96.f);
  float var  = sq * (1.f / 96.f) - mean * mean;
  float rstd = rsqrtf(var + EPSV);
  bf16* yp = y + p * CDIM;
  yp[lane] = f2b((v0 - mean) * rstd * gamma[lane] + beta[lane]);
  if (lane < 32)
    yp[64 + lane] = f2b((v1 - mean) * rstd * gamma[64 + lane] + beta[64 + lane]);
}

// ---- Tiled GEMM: out[M,N] = A[M,KA(bf16),lda] * W[KW,N (stride ldw)](f32) (+res) ----
template<bool ADD_RES, bool OUT_BF16>
__global__ __launch_bounds__(256) void gemm_kernel(
    const bf16* __restrict__ A, int lda,
    const float* __restrict__ W, int ldw, int N, int KW,
    void* __restrict__ outp, int ldo,
    const float* __restrict__ res, int ldr,
    int KA)
{
  constexpr int BM = 64, BN = 64, BK = 32;
  __shared__ __align__(16) float As[BK][BM + 4];
  __shared__ __align__(16) float Ws[BK][BN + 4];
  const int tid = threadIdx.x;
  const int bm = blockIdx.y * BM;
  const int bn = blockIdx.x * BN;
  const int tm = tid >> 4, tn = tid & 15;
  const int ar = tid >> 2;          // 0..63 row in A tile
  const int ak = (tid & 3) * 8;     // 0,8,16,24
  const int wr = tid >> 4;          // 0..15
  const int wc = (tid & 15) * 4;
  float acc[4][4] = {};
  for (int k0 = 0; k0 < KA; k0 += BK) {
    {
      const uint4 u = *reinterpret_cast<const uint4*>(A + (long)(bm + ar) * lda + k0 + ak);
      As[ak + 0][ar] = __uint_as_float(u.x << 16);
      As[ak + 1][ar] = __uint_as_float(u.x & 0xffff0000u);
      As[ak + 2][ar] = __uint_as_float(u.y << 16);
      As[ak + 3][ar] = __uint_as_float(u.y & 0xffff0000u);
      As[ak + 4][ar] = __uint_as_float(u.z << 16);
      As[ak + 5][ar] = __uint_as_float(u.z & 0xffff0000u);
      As[ak + 6][ar] = __uint_as_float(u.w << 16);
      As[ak + 7][ar] = __uint_as_float(u.w & 0xffff0000u);
    }
    #pragma unroll
    for (int h = 0; h < 2; ++h) {
      int k = k0 + wr + h * 16;
      #pragma unroll
      for (int j = 0; j < 4; ++j) {
        int n = bn + wc + j;
        float v = 0.f;
        if (k < KW && n < N) v = W[(long)k * ldw + n];
        Ws[wr + h * 16][wc + j] = v;
      }
    }
    __syncthreads();
    #pragma unroll
    for (int k = 0; k < BK; ++k) {
      float4 av = *reinterpret_cast<const float4*>(&As[k][tm * 4]);
      float4 bv = *reinterpret_cast<const float4*>(&Ws[k][tn * 4]);
      acc[0][0] += av.x * bv.x; acc[0][1] += av.x * bv.y; acc[0][2] += av.x * bv.z; acc[0][3] += av.x * bv.w;
      acc[1][0] += av.y * bv.x; acc[1][1] += av.y * bv.y; acc[1][2] += av.y * bv.z; acc[1][3] += av.y * bv.w;
      acc[2][0] += av.z * bv.x; acc[2][1] += av.z * bv.y; acc[2][2] += av.z * bv.z; acc[2][3] += av.z * bv.w;
      acc[3][0] += av.w * bv.x; acc[3][1] += av.w * bv.y; acc[3][2] += av.w * bv.z; acc[3][3] += av.w * bv.w;
    }
    __syncthreads();
  }
  #pragma unroll
  for (int i = 0; i < 4; ++i) {
    long row = bm + tm * 4 + i;
    #pragma unroll
    for (int j = 0; j < 4; ++j) {
      int col = bn + tn * 4 + j;
      if (col < N) {
        float v = acc[i][j];
        if (ADD_RES) v += res[row * ldr + col];
        if (OUT_BF16) ((bf16*)outp)[row * ldo + col] = f2b(v);
        else          ((float*)outp)[row * ldo + col] = v;
      }
    }
  }
}

// ======== Spatially-tiled depthwise 3x3 conv ========
// Block: 16x16 pixel tile, TC channels (chunk c0 = blockIdx.z*TC).
// LDS holds 18x18 halo tile x TC bf16, channel dim padded to TC+2 (2-way banks = free).
// Thread = (x 0..15, ygrp 0..3, chlane 0..3): 4 y-outputs x channel-pair per cp iter;
// 6 LDS rows reused across the 3 y-taps. Weights wave-uniform (chlane = wave id).
// MODE 0: out = conv;  MODE 1: out = gelu_exact(conv);  MODE 2: out *= conv (RMW).
// cmax guards weight reads for the garbage col (ffn col 255).
template<int LDC, int TC, int MODE>
__global__ __launch_bounds__(256) void dwconv_tiled(
    const bf16* __restrict__ in, const float* __restrict__ kw, int kws, int cmax,
    bf16* __restrict__ out, int ldo)
{
  constexpr int TCP = TC + 2;
  constexpr int VPP = TC / 8;            // 16B vectors per pixel
  constexpr int NV  = 18 * 18 * VPP;     // total vector loads
  __shared__ bf16 sm[18 * 18 * TCP];
  const int tid = threadIdx.x;
  const int tx0 = blockIdx.x * 16;
  const int ty0 = (blockIdx.y & 15) * 16;
  const int b   = blockIdx.y >> 4;
  const int c0  = blockIdx.z * TC;
  const long bbase = (long)b * HWSZ;

  for (int f = tid; f < NV; f += 256) {
    int row = f / (18 * VPP);
    int rem = f - row * (18 * VPP);
    int px  = rem / VPP;
    int v   = rem - px * VPP;
    int y = ty0 + row - 1, x = tx0 + px - 1;
    uint4 u = make_uint4(0u, 0u, 0u, 0u);
    if ((unsigned)y < (unsigned)HH && (unsigned)x < (unsigned)WW)
      u = *reinterpret_cast<const uint4*>(in + (bbase + (long)y * WW + x) * LDC + c0 + v * 8);
    unsigned* s = reinterpret_cast<unsigned*>(&sm[(row * 18 + px) * TCP + v * 8]);
    s[0] = u.x; s[1] = u.y; s[2] = u.z; s[3] = u.w;
  }
  __syncthreads();

  const int x   = tid & 15;
  const int yg  = (tid >> 4) & 3;
  const int chl = tid >> 6;
  for (int cp = chl; cp < TC / 2; cp += 4) {
    const int ch = 2 * cp;
    float w0[9], w1[9];
    #pragma unroll
    for (int t = 0; t < 9; ++t) {
      w0[t] = (c0 + ch     < cmax) ? kw[t * kws + c0 + ch]     : 0.f;
      w1[t] = (c0 + ch + 1 < cmax) ? kw[t * kws + c0 + ch + 1] : 0.f;
    }
    float r0[6][3], r1[6][3];
    #pragma unroll
    for (int rr = 0; rr < 6; ++rr)
      #pragma unroll
      for (int dx = 0; dx < 3; ++dx) {
        unsigned u = *reinterpret_cast<const unsigned*>(&sm[((yg * 4 + rr) * 18 + x + dx) * TCP + ch]);
        r0[rr][dx] = __uint_as_float(u << 16);
        r1[rr][dx] = __uint_as_float(u & 0xffff0000u);
      }
    #pragma unroll
    for (int yy = 0; yy < 4; ++yy) {
      float a0 = 0.f, a1 = 0.f;
      #pragma unroll
      for (int dy = 0; dy < 3; ++dy)
        #pragma unroll
        for (int dx = 0; dx < 3; ++dx) {
          a0 += r0[yy + dy][dx] * w0[dy * 3 + dx];
          a1 += r1[yy + dy][dx] * w1[dy * 3 + dx];
        }
      long po = bbase + (long)(ty0 + yg * 4 + yy) * WW + tx0 + x;
      bf16* op = out + po * ldo + c0 + ch;
      if (MODE == 0) {
        op[0] = f2b(a0); op[1] = f2b(a1);
      } else if (MODE == 1) {
        op[0] = f2b(0.5f * a0 * (1.f + erff(a0 * 0.70710678118654752440f)));
        op[1] = f2b(0.5f * a1 * (1.f + erff(a1 * 0.70710678118654752440f)));
      } else {
        op[0] = f2b(b2f(op[0]) * a0);
        op[1] = f2b(b2f(op[1]) * a1);
      }
    }
  }
}

// ---------------- q/k spatial sum-of-squares (for L2 norms) ----------------
__global__ __launch_bounds__(192) void qknorm_kernel(const bf16* __restrict__ qkv,
    float* __restrict__ nq, float* __restrict__ nk)
{
  int col = threadIdx.x;            // 0..191 = q cols 0..95, k cols 96..191
  long row0 = (long)blockIdx.x * 128;
  float s = 0.f;
  for (int r = 0; r < 128; ++r) {
    float v = b2f(qkv[(row0 + r) * C3 + col]);
    s += v * v;
  }
  int b = (int)(row0 >> 16);
  if (col < CDIM) atomicAdd(&nq[b * CDIM + col], s);
  else            atomicAdd(&nk[b * CDIM + col - CDIM], s);
}

// ------- Gram matrix G[b,head,c,d] = sum_s q*k (raw, pre-normalization) -------
__global__ __launch_bounds__(256) void gram_kernel(const bf16* __restrict__ qkv,
    float* __restrict__ G)
{
  int bh = blockIdx.x >> 6;         // 0..3 = b*2+head
  int chunk = blockIdx.x & 63;
  int b = bh >> 1, head = bh & 1;
  long row0 = (long)b * HWSZ + (long)chunk * 1024;
  __shared__ float qs[64][CH], ks[64][CH];
  int tid = threadIdx.x;
  int c0 = (tid >> 4) * 3, d0 = (tid & 15) * 3;
  float acc[3][3] = {};
  for (int it = 0; it < 16; ++it) {
    for (int f = tid; f < 64 * CH; f += 256) {
      int pix = f / CH, cc = f % CH;
      long base = (row0 + it * 64 + pix) * C3 + head * CH;
      qs[pix][cc] = b2f(qkv[base + cc]);
      ks[pix][cc] = b2f(qkv[base + CDIM + cc]);
    }
    __syncthreads();
    for (int s = 0; s < 64; ++s) {
      float q0 = qs[s][c0], q1 = qs[s][c0 + 1], q2 = qs[s][c0 + 2];
      float k0 = ks[s][d0], k1 = ks[s][d0 + 1], k2 = ks[s][d0 + 2];
      acc[0][0] += q0 * k0; acc[0][1] += q0 * k1; acc[0][2] += q0 * k2;
      acc[1][0] += q1 * k0; acc[1][1] += q1 * k1; acc[1][2] += q1 * k2;
      acc[2][0] += q2 * k0; acc[2][1] += q2 * k1; acc[2][2] += q2 * k2;
    }
    __syncthreads();
  }
  float* Gp = G + (long)bh * CH * CH;
  #pragma unroll
  for (int i = 0; i < 3; ++i)
    #pragma unroll
    for (int j = 0; j < 3; ++j)
      atomicAdd(&Gp[(c0 + i) * CH + d0 + j], acc[i][j]);
}

// ---------------- softmax over d of G/(|q||k|)*temp ----------------
__global__ __launch_bounds__(64) void softmax_kernel(const float* __restrict__ G,
    const float* __restrict__ nq, const float* __restrict__ nk,
    const float* __restrict__ temp, float* __restrict__ attn)
{
  int r = blockIdx.x;               // 0..191 = (b*2+head)*48 + c
  int lane = threadIdx.x;
  int bh = r / CH, c = r % CH;
  int b = bh >> 1, head = bh & 1;
  float t  = temp[head];
  float qn = sqrtf(nq[b * CDIM + head * CH + c]);
  float val = 0.f, v = -INFINITY;
  if (lane < CH) {
    float kn = sqrtf(nk[b * CDIM + head * CH + lane]);
    val = G[r * CH + lane] / (qn * kn) * t;
    v = val;
  }
  float m = v;
  #pragma unroll
  for (int off = 32; off; off >>= 1) m = fmaxf(m, __shfl_xor(m, off));
  float e = (lane < CH) ? expf(val - m) : 0.f;
  float s = e;
  #pragma unroll
  for (int off = 32; off; off >>= 1) s += __shfl_xor(s, off);
  if (lane < CH) attn[r * CH + lane] = e / s;
}

// ---- o[p,c] = sum_d attn[head(c)][c%48][d] * v[p, head*48+d] ----
__global__ __launch_bounds__(256) void applyattn_kernel(const bf16* __restrict__ qkv,
    const float* __restrict__ attn, bf16* __restrict__ o)
{
  __shared__ float As[2 * CH * CH];   // 4608 f32
  __shared__ bf16  vs[64][CDIM];
  long p0 = (long)blockIdx.x * 64;
  int b = (int)(p0 >> 16);
  int tid = threadIdx.x;
  for (int f = tid; f < 2 * CH * CH; f += 256) As[f] = attn[(long)b * 2 * CH * CH + f];
  for (int f = tid; f < 64 * CDIM; f += 256) {
    int pix = f / CDIM, cc = f % CDIM;
    vs[pix][cc] = qkv[(p0 + pix) * C3 + 2 * CDIM + cc];
  }
  __syncthreads();
  for (int f = tid; f < 64 * CDIM; f += 256) {
    int pix = f / CDIM, cc = f % CDIM;
    int head = cc / CH, hc = cc % CH;
    const float* Ap = As + (head * CH + hc) * CH;
    const bf16* vp = &vs[pix][head * CH];
    float acc = 0.f;
    #pragma unroll
    for (int d = 0; d < CH; ++d) acc += Ap[d] * b2f(vp[d]);
    o[(p0 + pix) * CDIM + cc] = f2b(acc);
  }
}

extern "C" void kernel_launch(void* const* d_in, const int* in_sizes, int n_in,
                              void* d_out, int out_size, void* d_ws, size_t ws_size,
                              hipStream_t stream)
{
  const float* x          = (const float*)d_in[0];
  const float* ln1_g      = (const float*)d_in[1];
  const float* ln1_b      = (const float*)d_in[2];
  const float* ln2_g      = (const float*)d_in[3];
  const float* ln2_b      = (const float*)d_in[4];
  const float* qkv_w      = (const float*)d_in[5];
  const float* qkv_dw     = (const float*)d_in[6];
  const float* temp       = (const float*)d_in[7];
  const float* attn_out_w = (const float*)d_in[8];
  const float* ffn_in_w   = (const float*)d_in[9];
  const float* ffn_dw     = (const float*)d_in[10];
  const float* ffn_out_w  = (const float*)d_in[11];
  float* out = (float*)d_out;

  // workspace layout (peak ~168.1 MB)
  char* ws = (char*)d_ws;
  size_t off = 0;
  auto alloc = [&](size_t bytes) { void* p = ws + off; off += (bytes + 255) & ~(size_t)255; return p; };
  bf16*  BA  = (bf16*)alloc((size_t)NPIX * C3 * 2);    // "A": qkv post-dwconv; later gelu(x1)/gated
  bf16*  BB  = (bf16*)alloc((size_t)NPIX * C3 * 2);    // "B": qkv pre-dwconv; later t1/t2
  bf16*  BC  = (bf16*)alloc((size_t)NPIX * CDIM * 2);  // "C": ln output / o
  float* NQ  = (float*)alloc(BATCH * CDIM * 4);
  float* NK  = (float*)alloc(BATCH * CDIM * 4);
  float* G   = (float*)alloc(BATCH * HEADS * CH * CH * 4);
  float* ATT = (float*)alloc(BATCH * HEADS * CH * CH * 4);
  hipMemsetAsync(NQ, 0, (size_t)(768 + 768 + 36864), stream);

  // ---- attention branch ----
  ln_kernel<<<NPIX / 4, 256, 0, stream>>>(x, ln1_g, ln1_b, BC);
  {
    dim3 g((C3 + 63) / 64, NPIX / 64);
    gemm_kernel<false, true><<<g, 256, 0, stream>>>(BC, CDIM, qkv_w, C3, C3, CDIM, BB, C3, nullptr, 0, CDIM);
  }
  dwconv_tiled<C3, 48, 0><<<dim3(16, 32, 6), 256, 0, stream>>>(BB, qkv_dw, C3, C3, BA, C3);
  qknorm_kernel<<<1024, 192, 0, stream>>>(BA, NQ, NK);
  gram_kernel<<<256, 256, 0, stream>>>(BA, G);
  softmax_kernel<<<192, 64, 0, stream>>>(G, NQ, NK, temp, ATT);
  applyattn_kernel<<<NPIX / 64, 256, 0, stream>>>(BA, ATT, BC);
  {
    dim3 g((CDIM + 63) / 64, NPIX / 64);
    gemm_kernel<true, false><<<g, 256, 0, stream>>>(BC, CDIM, attn_out_w, CDIM, CDIM, CDIM, out, CDIM, x, CDIM, CDIM);
  }

  // ---- FFN branch (hidden split into two 255-col halves) ----
  ln_kernel<<<NPIX / 4, 256, 0, stream>>>(out, ln2_g, ln2_b, BC);
  {
    dim3 g((HIDN + 63) / 64, NPIX / 64);
    gemm_kernel<false, true><<<g, 256, 0, stream>>>(BC, CDIM, ffn_in_w, 2 * HIDN, HIDN, CDIM, BB, 256, nullptr, 0, CDIM);
  }
  dwconv_tiled<256, 64, 1><<<dim3(16, 32, 4), 256, 0, stream>>>(BB, ffn_dw, 2 * HIDN, HIDN, BA, 256);
  {
    dim3 g((HIDN + 63) / 64, NPIX / 64);
    gemm_kernel<false, true><<<g, 256, 0, stream>>>(BC, CDIM, ffn_in_w + HIDN, 2 * HIDN, HIDN, CDIM, BB, 256, nullptr, 0, CDIM);
  }
  dwconv_tiled<256, 64, 2><<<dim3(16, 32, 4), 256, 0, stream>>>(BB, ffn_dw + HIDN, 2 * HIDN, HIDN, BA, 256);
  {
    dim3 g((CDIM + 63) / 64, NPIX / 64);
    gemm_kernel<true, false><<<g, 256, 0, stream>>>(BA, 256, ffn_out_w, CDIM, CDIM, HIDN, out, CDIM, out, CDIM, 256);
  }
}

// Round 4
// 832.420 us; speedup vs baseline: 1.9506x; 1.5191x over previous
//
#include <hip/hip_runtime.h>
#include <hip/hip_bf16.h>

typedef __hip_bfloat16 bf16;
typedef __attribute__((ext_vector_type(8))) short short8;
typedef __attribute__((ext_vector_type(4))) float floatx4;

#define NPIX  131072
#define BATCH 2
#define HH    256
#define WW    256
#define CDIM  96
#define C3    288
#define HEADS 2
#define CH    48
#define HIDN  255
#define HWSZ  65536
#define EPSV  1e-5f

__device__ __forceinline__ float b2f(bf16 v) { return __bfloat162float(v); }
__device__ __forceinline__ bf16  f2b(float v) { return __float2bfloat16(v); }
__device__ __forceinline__ float lo16(unsigned u) { return __uint_as_float(u << 16); }
__device__ __forceinline__ float hi16(unsigned u) { return __uint_as_float(u & 0xffff0000u); }

// ---------------- LayerNorm: fp32 in -> bf16 out, one wave per pixel ----------------
__global__ __launch_bounds__(256) void ln_kernel(const float* __restrict__ x,
    const float* __restrict__ gamma, const float* __restrict__ beta,
    bf16* __restrict__ y)
{
  int wave = threadIdx.x >> 6;
  int lane = threadIdx.x & 63;
  long p = (long)blockIdx.x * 4 + wave;
  const float* xp = x + p * CDIM;
  float v0 = xp[lane];
  float v1 = (lane < 32) ? xp[64 + lane] : 0.f;
  float s  = v0 + v1;
  float sq = v0 * v0 + v1 * v1;
  #pragma unroll
  for (int off = 32; off; off >>= 1) {
    s  += __shfl_xor(s, off);
    sq += __shfl_xor(sq, off);
  }
  float mean = s * (1.f / 96.f);
  float var  = sq * (1.f / 96.f) - mean * mean;
  float rstd = rsqrtf(var + EPSV);
  bf16* yp = y + p * CDIM;
  yp[lane] = f2b((v0 - mean) * rstd * gamma[lane] + beta[lane]);
  if (lane < 32)
    yp[64 + lane] = f2b((v1 - mean) * rstd * gamma[64 + lane] + beta[64 + lane]);
}

// ======== MFMA GEMM: out[M,N] = A[M,KT bf16,lda] * W[KW,N fp32,ldw] (+res) ========
// Block: 4 waves x 64 rows = 256 rows, BN cols. KT = K padded to mult of 32;
// A must be loadable over KT cols (garbage cols OK: Bs[k>=KW]=0).
// B staged in LDS as Bs[n][k] bf16, KP == 32 (mod 64) -> 2-way bank alias (free).
// mfma_f32_16x16x32_bf16 layouts: A[m=lane&15][k=quad*8+j], B[k=quad*8+j][n=lane&15],
// C/D: col=lane&15, row=quad*4+reg.
template<int BN, int KT, bool ADD_RES, bool OUT_BF16>
__global__ __launch_bounds__(256) void mfma_gemm(
    const bf16* __restrict__ A, int lda,
    const float* __restrict__ W, int ldw, int N, int KW,
    void* __restrict__ outp, int ldo,
    const float* __restrict__ res, int ldr)
{
  constexpr int KP = (KT % 64 == 32) ? KT : KT + 32;
  constexpr int NK = KT / 32;
  constexpr int NCT = BN / 16;
  __shared__ __align__(16) bf16 Bs[BN * KP];
  const int tid  = threadIdx.x;
  const int bn   = blockIdx.x * BN;
  const long bm  = (long)blockIdx.y * 256;
  const int lane = tid & 63;
  const int wv   = tid >> 6;
  const int m15  = lane & 15;
  const int quad = lane >> 4;

  // stage W tile -> Bs (coalesced along n; zeros beyond KW/N)
  for (int idx = tid; idx < KT * BN; idx += 256) {
    int k = idx / BN, n = idx - k * BN;
    float v = 0.f;
    if (k < KW && bn + n < N) v = W[(long)k * ldw + bn + n];
    Bs[n * KP + k] = f2b(v);
  }

  const bf16* Arow[4];
  #pragma unroll
  for (int rt = 0; rt < 4; ++rt)
    Arow[rt] = A + (bm + wv * 64 + rt * 16 + m15) * lda + quad * 8;

  short8 cur[4], nxt[4];
  #pragma unroll
  for (int rt = 0; rt < 4; ++rt) cur[rt] = *reinterpret_cast<const short8*>(Arow[rt]);

  __syncthreads();

  floatx4 acc[4][NCT];
  #pragma unroll
  for (int rt = 0; rt < 4; ++rt)
    #pragma unroll
    for (int ct = 0; ct < NCT; ++ct)
      acc[rt][ct] = (floatx4){0.f, 0.f, 0.f, 0.f};

  #pragma unroll
  for (int kk = 0; kk < NK; ++kk) {
    if (kk + 1 < NK) {
      #pragma unroll
      for (int rt = 0; rt < 4; ++rt)
        nxt[rt] = *reinterpret_cast<const short8*>(Arow[rt] + (kk + 1) * 32);
    }
    #pragma unroll
    for (int ct = 0; ct < NCT; ++ct) {
      short8 b = *reinterpret_cast<const short8*>(&Bs[(ct * 16 + m15) * KP + kk * 32 + quad * 8]);
      #pragma unroll
      for (int rt = 0; rt < 4; ++rt)
        acc[rt][ct] = __builtin_amdgcn_mfma_f32_16x16x32_bf16(cur[rt], b, acc[rt][ct], 0, 0, 0);
    }
    #pragma unroll
    for (int rt = 0; rt < 4; ++rt) cur[rt] = nxt[rt];
  }

  #pragma unroll
  for (int rt = 0; rt < 4; ++rt)
    #pragma unroll
    for (int ct = 0; ct < NCT; ++ct) {
      int col = bn + ct * 16 + m15;
      if (col < N) {
        #pragma unroll
        for (int r = 0; r < 4; ++r) {
          long row = bm + wv * 64 + rt * 16 + quad * 4 + r;
          float v = acc[rt][ct][r];
          if (ADD_RES) v += res[row * ldr + col];
          if (OUT_BF16) ((bf16*)outp)[row * ldo + col] = f2b(v);
          else          ((float*)outp)[row * ldo + col] = v;
        }
      }
    }
}

// ======== Spatially-tiled depthwise 3x3 conv, vectorized 8-ch I/O ========
// Block: 16x16 pixel tile, TC channels. LDS: [cg][18*18] uint4 planes (cg = 8-ch group).
// Thread = (x, ygrp, wave=chl): 4 y outputs x 8 channels per cg iter; 16-B loads/stores.
// MODE 0: out = conv;  MODE 1: out = gelu_exact(conv);  MODE 2: out *= conv (RMW, 16B).
template<int LDC, int TC, int MODE>
__global__ __launch_bounds__(256) void dwconv_tiled(
    const bf16* __restrict__ in, const float* __restrict__ kw, int kws, int cmax,
    bf16* __restrict__ out, int ldo)
{
  constexpr int VPP = TC / 8;
  __shared__ uint4 sm[VPP][18 * 18];
  const int tid = threadIdx.x;
  const int tx0 = blockIdx.x * 16;
  const int ty0 = (blockIdx.y & 15) * 16;
  const int b   = blockIdx.y >> 4;
  const int c0  = blockIdx.z * TC;
  const long bbase = (long)b * HWSZ;

  for (int f = tid; f < 18 * 18 * VPP; f += 256) {
    int pix = f / VPP;
    int v   = f - pix * VPP;
    int row = pix / 18, px = pix - row * 18;
    int y = ty0 + row - 1, x = tx0 + px - 1;
    uint4 u = make_uint4(0u, 0u, 0u, 0u);
    if ((unsigned)y < (unsigned)HH && (unsigned)x < (unsigned)WW)
      u = *reinterpret_cast<const uint4*>(in + (bbase + (long)y * WW + x) * LDC + c0 + v * 8);
    sm[v][pix] = u;
  }
  __syncthreads();

  const int x   = tid & 15;
  const int yg  = (tid >> 4) & 3;
  const int chl = tid >> 6;
  for (int cg = chl; cg < VPP; cg += 4) {
    const int cb = c0 + cg * 8;
    float wgt[9][8];
    #pragma unroll
    for (int t = 0; t < 9; ++t)
      #pragma unroll
      for (int j = 0; j < 8; ++j)
        wgt[t][j] = (cb + j < cmax) ? kw[t * kws + cb + j] : 0.f;

    #pragma unroll
    for (int yy = 0; yy < 4; ++yy) {
      const int ry = yg * 4 + yy;
      float acc[8] = {0.f, 0.f, 0.f, 0.f, 0.f, 0.f, 0.f, 0.f};
      #pragma unroll
      for (int dy = 0; dy < 3; ++dy)
        #pragma unroll
        for (int dx = 0; dx < 3; ++dx) {
          uint4 u = sm[cg][(ry + dy) * 18 + x + dx];
          const float* wt = wgt[dy * 3 + dx];
          acc[0] += lo16(u.x) * wt[0]; acc[1] += hi16(u.x) * wt[1];
          acc[2] += lo16(u.y) * wt[2]; acc[3] += hi16(u.y) * wt[3];
          acc[4] += lo16(u.z) * wt[4]; acc[5] += hi16(u.z) * wt[5];
          acc[6] += lo16(u.w) * wt[6]; acc[7] += hi16(u.w) * wt[7];
        }
      long po = bbase + (long)(ty0 + yg * 4 + yy) * WW + tx0 + x;
      bf16* op = out + po * ldo + cb;
      __align__(16) bf16 ov[8];
      if (MODE == 0) {
        #pragma unroll
        for (int j = 0; j < 8; ++j) ov[j] = f2b(acc[j]);
      } else if (MODE == 1) {
        #pragma unroll
        for (int j = 0; j < 8; ++j)
          ov[j] = f2b(0.5f * acc[j] * (1.f + erff(acc[j] * 0.70710678118654752440f)));
      } else {
        uint4 old = *reinterpret_cast<const uint4*>(op);
        ov[0] = f2b(lo16(old.x) * acc[0]); ov[1] = f2b(hi16(old.x) * acc[1]);
        ov[2] = f2b(lo16(old.y) * acc[2]); ov[3] = f2b(hi16(old.y) * acc[3]);
        ov[4] = f2b(lo16(old.z) * acc[4]); ov[5] = f2b(hi16(old.z) * acc[5]);
        ov[6] = f2b(lo16(old.w) * acc[6]); ov[7] = f2b(hi16(old.w) * acc[7]);
      }
      *reinterpret_cast<uint4*>(op) = *reinterpret_cast<const uint4*>(ov);
    }
  }
}

// ---------------- q/k spatial sum-of-squares (for L2 norms) ----------------
__global__ __launch_bounds__(192) void qknorm_kernel(const bf16* __restrict__ qkv,
    float* __restrict__ nq, float* __restrict__ nk)
{
  int col = threadIdx.x;            // 0..191 = q cols 0..95, k cols 96..191
  long row0 = (long)blockIdx.x * 128;
  float s = 0.f;
  for (int r = 0; r < 128; ++r) {
    float v = b2f(qkv[(row0 + r) * C3 + col]);
    s += v * v;
  }
  int b = (int)(row0 >> 16);
  if (col < CDIM) atomicAdd(&nq[b * CDIM + col], s);
  else            atomicAdd(&nk[b * CDIM + col - CDIM], s);
}

// ------- Gram matrix G[b,head,c,d] = sum_s q*k (raw, pre-normalization) -------
__global__ __launch_bounds__(256) void gram_kernel(const bf16* __restrict__ qkv,
    float* __restrict__ G)
{
  int bh = blockIdx.x >> 6;         // 0..3 = b*2+head
  int chunk = blockIdx.x & 63;
  int b = bh >> 1, head = bh & 1;
  long row0 = (long)b * HWSZ + (long)chunk * 1024;
  __shared__ float qs[64][CH], ks[64][CH];
  int tid = threadIdx.x;
  int c0 = (tid >> 4) * 3, d0 = (tid & 15) * 3;
  float acc[3][3] = {};
  for (int it = 0; it < 16; ++it) {
    for (int f = tid; f < 64 * CH; f += 256) {
      int pix = f / CH, cc = f % CH;
      long base = (row0 + it * 64 + pix) * C3 + head * CH;
      qs[pix][cc] = b2f(qkv[base + cc]);
      ks[pix][cc] = b2f(qkv[base + CDIM + cc]);
    }
    __syncthreads();
    for (int s = 0; s < 64; ++s) {
      float q0 = qs[s][c0], q1 = qs[s][c0 + 1], q2 = qs[s][c0 + 2];
      float k0 = ks[s][d0], k1 = ks[s][d0 + 1], k2 = ks[s][d0 + 2];
      acc[0][0] += q0 * k0; acc[0][1] += q0 * k1; acc[0][2] += q0 * k2;
      acc[1][0] += q1 * k0; acc[1][1] += q1 * k1; acc[1][2] += q1 * k2;
      acc[2][0] += q2 * k0; acc[2][1] += q2 * k1; acc[2][2] += q2 * k2;
    }
    __syncthreads();
  }
  float* Gp = G + (long)bh * CH * CH;
  #pragma unroll
  for (int i = 0; i < 3; ++i)
    #pragma unroll
    for (int j = 0; j < 3; ++j)
      atomicAdd(&Gp[(c0 + i) * CH + d0 + j], acc[i][j]);
}

// ---------------- softmax over d of G/(|q||k|)*temp ----------------
__global__ __launch_bounds__(64) void softmax_kernel(const float* __restrict__ G,
    const float* __restrict__ nq, const float* __restrict__ nk,
    const float* __restrict__ temp, float* __restrict__ attn)
{
  int r = blockIdx.x;               // 0..191 = (b*2+head)*48 + c
  int lane = threadIdx.x;
  int bh = r / CH, c = r % CH;
  int b = bh >> 1, head = bh & 1;
  float t  = temp[head];
  float qn = sqrtf(nq[b * CDIM + head * CH + c]);
  float val = 0.f, v = -INFINITY;
  if (lane < CH) {
    float kn = sqrtf(nk[b * CDIM + head * CH + lane]);
    val = G[r * CH + lane] / (qn * kn) * t;
    v = val;
  }
  float m = v;
  #pragma unroll
  for (int off = 32; off; off >>= 1) m = fmaxf(m, __shfl_xor(m, off));
  float e = (lane < CH) ? expf(val - m) : 0.f;
  float s = e;
  #pragma unroll
  for (int off = 32; off; off >>= 1) s += __shfl_xor(s, off);
  if (lane < CH) attn[r * CH + lane] = e / s;
}

// ---- o[p,c] = sum_d attn[head(c)][c%48][d] * v[p, head*48+d] ----
__global__ __launch_bounds__(256) void applyattn_kernel(const bf16* __restrict__ qkv,
    const float* __restrict__ attn, bf16* __restrict__ o)
{
  __shared__ float As[2 * CH * CH];   // 4608 f32
  __shared__ bf16  vs[64][CDIM];
  long p0 = (long)blockIdx.x * 64;
  int b = (int)(p0 >> 16);
  int tid = threadIdx.x;
  for (int f = tid; f < 2 * CH * CH; f += 256) As[f] = attn[(long)b * 2 * CH * CH + f];
  for (int f = tid; f < 64 * CDIM; f += 256) {
    int pix = f / CDIM, cc = f % CDIM;
    vs[pix][cc] = qkv[(p0 + pix) * C3 + 2 * CDIM + cc];
  }
  __syncthreads();
  for (int f = tid; f < 64 * CDIM; f += 256) {
    int pix = f / CDIM, cc = f % CDIM;
    int head = cc / CH, hc = cc % CH;
    const float* Ap = As + (head * CH + hc) * CH;
    const bf16* vp = &vs[pix][head * CH];
    float acc = 0.f;
    #pragma unroll
    for (int d = 0; d < CH; ++d) acc += Ap[d] * b2f(vp[d]);
    o[(p0 + pix) * CDIM + cc] = f2b(acc);
  }
}

extern "C" void kernel_launch(void* const* d_in, const int* in_sizes, int n_in,
                              void* d_out, int out_size, void* d_ws, size_t ws_size,
                              hipStream_t stream)
{
  const float* x          = (const float*)d_in[0];
  const float* ln1_g      = (const float*)d_in[1];
  const float* ln1_b      = (const float*)d_in[2];
  const float* ln2_g      = (const float*)d_in[3];
  const float* ln2_b      = (const float*)d_in[4];
  const float* qkv_w      = (const float*)d_in[5];
  const float* qkv_dw     = (const float*)d_in[6];
  const float* temp       = (const float*)d_in[7];
  const float* attn_out_w = (const float*)d_in[8];
  const float* ffn_in_w   = (const float*)d_in[9];
  const float* ffn_dw     = (const float*)d_in[10];
  const float* ffn_out_w  = (const float*)d_in[11];
  float* out = (float*)d_out;

  // workspace layout (peak ~168.1 MB)
  char* ws = (char*)d_ws;
  size_t off = 0;
  auto alloc = [&](size_t bytes) { void* p = ws + off; off += (bytes + 255) & ~(size_t)255; return p; };
  bf16*  BA  = (bf16*)alloc((size_t)NPIX * C3 * 2);    // qkv post-dwconv; later gelu(x1)/gated
  bf16*  BB  = (bf16*)alloc((size_t)NPIX * C3 * 2);    // qkv pre-dwconv; later t1/t2
  bf16*  BC  = (bf16*)alloc((size_t)NPIX * CDIM * 2);  // ln output / o
  float* NQ  = (float*)alloc(BATCH * CDIM * 4);
  float* NK  = (float*)alloc(BATCH * CDIM * 4);
  float* G   = (float*)alloc(BATCH * HEADS * CH * CH * 4);
  float* ATT = (float*)alloc(BATCH * HEADS * CH * CH * 4);
  hipMemsetAsync(NQ, 0, (size_t)(768 + 768 + 36864), stream);

  // ---- attention branch ----
  ln_kernel<<<NPIX / 4, 256, 0, stream>>>(x, ln1_g, ln1_b, BC);
  mfma_gemm<48, 96, false, true><<<dim3(6, NPIX / 256), 256, 0, stream>>>(
      BC, CDIM, qkv_w, C3, C3, CDIM, BB, C3, nullptr, 0);
  dwconv_tiled<C3, 48, 0><<<dim3(16, 32, 6), 256, 0, stream>>>(BB, qkv_dw, C3, C3, BA, C3);
  qknorm_kernel<<<1024, 192, 0, stream>>>(BA, NQ, NK);
  gram_kernel<<<256, 256, 0, stream>>>(BA, G);
  softmax_kernel<<<192, 64, 0, stream>>>(G, NQ, NK, temp, ATT);
  applyattn_kernel<<<NPIX / 64, 256, 0, stream>>>(BA, ATT, BC);
  mfma_gemm<48, 96, true, false><<<dim3(2, NPIX / 256), 256, 0, stream>>>(
      BC, CDIM, attn_out_w, CDIM, CDIM, CDIM, out, CDIM, x, CDIM);

  // ---- FFN branch (hidden split into two 255-col halves) ----
  ln_kernel<<<NPIX / 4, 256, 0, stream>>>(out, ln2_g, ln2_b, BC);
  mfma_gemm<64, 96, false, true><<<dim3(4, NPIX / 256), 256, 0, stream>>>(
      BC, CDIM, ffn_in_w, 2 * HIDN, HIDN, CDIM, BB, 256, nullptr, 0);
  dwconv_tiled<256, 64, 1><<<dim3(16, 32, 4), 256, 0, stream>>>(BB, ffn_dw, 2 * HIDN, HIDN, BA, 256);
  mfma_gemm<64, 96, false, true><<<dim3(4, NPIX / 256), 256, 0, stream>>>(
      BC, CDIM, ffn_in_w + HIDN, 2 * HIDN, HIDN, CDIM, BB, 256, nullptr, 0);
  dwconv_tiled<256, 64, 2><<<dim3(16, 32, 4), 256, 0, stream>>>(BB, ffn_dw + HIDN, 2 * HIDN, HIDN, BA, 256);
  mfma_gemm<48, 256, true, false><<<dim3(2, NPIX / 256), 256, 0, stream>>>(
      BA, 256, ffn_out_w, CDIM, CDIM, HIDN, out, CDIM, out, CDIM);
}

// Round 5
// 772.639 us; speedup vs baseline: 2.1015x; 1.0774x over previous
//
#include <hip/hip_runtime.h>
#include <hip/hip_bf16.h>

typedef __hip_bfloat16 bf16;
typedef __attribute__((ext_vector_type(8))) short short8;
typedef __attribute__((ext_vector_type(4))) float floatx4;

#define NPIX  131072
#define BATCH 2
#define HH    256
#define WW    256
#define CDIM  96
#define C3    288
#define HEADS 2
#define CH    48
#define HIDN  255
#define HWSZ  65536
#define EPSV  1e-5f

__device__ __forceinline__ float b2f(bf16 v) { return __bfloat162float(v); }
__device__ __forceinline__ bf16  f2b(float v) { return __float2bfloat16(v); }
__device__ __forceinline__ float lo16(unsigned u) { return __uint_as_float(u << 16); }
__device__ __forceinline__ float hi16(unsigned u) { return __uint_as_float(u & 0xffff0000u); }

// ---------------- LayerNorm: fp32 in -> bf16 out, one wave per pixel ----------------
__global__ __launch_bounds__(256) void ln_kernel(const float* __restrict__ x,
    const float* __restrict__ gamma, const float* __restrict__ beta,
    bf16* __restrict__ y)
{
  int wave = threadIdx.x >> 6;
  int lane = threadIdx.x & 63;
  long p = (long)blockIdx.x * 4 + wave;
  const float* xp = x + p * CDIM;
  float v0 = xp[lane];
  float v1 = (lane < 32) ? xp[64 + lane] : 0.f;
  float s  = v0 + v1;
  float sq = v0 * v0 + v1 * v1;
  #pragma unroll
  for (int off = 32; off; off >>= 1) {
    s  += __shfl_xor(s, off);
    sq += __shfl_xor(sq, off);
  }
  float mean = s * (1.f / 96.f);
  float var  = sq * (1.f / 96.f) - mean * mean;
  float rstd = rsqrtf(var + EPSV);
  bf16* yp = y + p * CDIM;
  yp[lane] = f2b((v0 - mean) * rstd * gamma[lane] + beta[lane]);
  if (lane < 32)
    yp[64 + lane] = f2b((v1 - mean) * rstd * gamma[64 + lane] + beta[64 + lane]);
}

// ======== MFMA GEMM: out[M,N] = A[M,KT bf16,lda] * W[KW,N fp32,ldw] (+res) ========
template<int BN, int KT, bool ADD_RES, bool OUT_BF16>
__global__ __launch_bounds__(256) void mfma_gemm(
    const bf16* __restrict__ A, int lda,
    const float* __restrict__ W, int ldw, int N, int KW,
    void* __restrict__ outp, int ldo,
    const float* __restrict__ res, int ldr)
{
  constexpr int KP = (KT % 64 == 32) ? KT : KT + 32;
  constexpr int NK = KT / 32;
  constexpr int NCT = BN / 16;
  __shared__ __align__(16) bf16 Bs[BN * KP];
  const int tid  = threadIdx.x;
  const int bn   = blockIdx.x * BN;
  const long bm  = (long)blockIdx.y * 256;
  const int lane = tid & 63;
  const int wv   = tid >> 6;
  const int m15  = lane & 15;
  const int quad = lane >> 4;

  for (int idx = tid; idx < KT * BN; idx += 256) {
    int k = idx / BN, n = idx - k * BN;
    float v = 0.f;
    if (k < KW && bn + n < N) v = W[(long)k * ldw + bn + n];
    Bs[n * KP + k] = f2b(v);
  }

  const bf16* Arow[4];
  #pragma unroll
  for (int rt = 0; rt < 4; ++rt)
    Arow[rt] = A + (bm + wv * 64 + rt * 16 + m15) * lda + quad * 8;

  short8 cur[4], nxt[4];
  #pragma unroll
  for (int rt = 0; rt < 4; ++rt) cur[rt] = *reinterpret_cast<const short8*>(Arow[rt]);

  __syncthreads();

  floatx4 acc[4][NCT];
  #pragma unroll
  for (int rt = 0; rt < 4; ++rt)
    #pragma unroll
    for (int ct = 0; ct < NCT; ++ct)
      acc[rt][ct] = (floatx4){0.f, 0.f, 0.f, 0.f};

  #pragma unroll
  for (int kk = 0; kk < NK; ++kk) {
    if (kk + 1 < NK) {
      #pragma unroll
      for (int rt = 0; rt < 4; ++rt)
        nxt[rt] = *reinterpret_cast<const short8*>(Arow[rt] + (kk + 1) * 32);
    }
    #pragma unroll
    for (int ct = 0; ct < NCT; ++ct) {
      short8 b = *reinterpret_cast<const short8*>(&Bs[(ct * 16 + m15) * KP + kk * 32 + quad * 8]);
      #pragma unroll
      for (int rt = 0; rt < 4; ++rt)
        acc[rt][ct] = __builtin_amdgcn_mfma_f32_16x16x32_bf16(cur[rt], b, acc[rt][ct], 0, 0, 0);
    }
    #pragma unroll
    for (int rt = 0; rt < 4; ++rt) cur[rt] = nxt[rt];
  }

  #pragma unroll
  for (int rt = 0; rt < 4; ++rt)
    #pragma unroll
    for (int ct = 0; ct < NCT; ++ct) {
      int col = bn + ct * 16 + m15;
      if (col < N) {
        #pragma unroll
        for (int r = 0; r < 4; ++r) {
          long row = bm + wv * 64 + rt * 16 + quad * 4 + r;
          float v = acc[rt][ct][r];
          if (ADD_RES) v += res[row * ldr + col];
          if (OUT_BF16) ((bf16*)outp)[row * ldo + col] = f2b(v);
          else          ((float*)outp)[row * ldo + col] = v;
        }
      }
    }
}

// ======== Spatially-tiled depthwise 3x3 conv, vectorized 8-ch I/O ========
template<int LDC, int TC, int MODE>
__global__ __launch_bounds__(256) void dwconv_tiled(
    const bf16* __restrict__ in, const float* __restrict__ kw, int kws, int cmax,
    bf16* __restrict__ out, int ldo)
{
  constexpr int VPP = TC / 8;
  __shared__ uint4 sm[VPP][18 * 18];
  const int tid = threadIdx.x;
  const int tx0 = blockIdx.x * 16;
  const int ty0 = (blockIdx.y & 15) * 16;
  const int b   = blockIdx.y >> 4;
  const int c0  = blockIdx.z * TC;
  const long bbase = (long)b * HWSZ;

  for (int f = tid; f < 18 * 18 * VPP; f += 256) {
    int pix = f / VPP;
    int v   = f - pix * VPP;
    int row = pix / 18, px = pix - row * 18;
    int y = ty0 + row - 1, x = tx0 + px - 1;
    uint4 u = make_uint4(0u, 0u, 0u, 0u);
    if ((unsigned)y < (unsigned)HH && (unsigned)x < (unsigned)WW)
      u = *reinterpret_cast<const uint4*>(in + (bbase + (long)y * WW + x) * LDC + c0 + v * 8);
    sm[v][pix] = u;
  }
  __syncthreads();

  const int x   = tid & 15;
  const int yg  = (tid >> 4) & 3;
  const int chl = tid >> 6;
  for (int cg = chl; cg < VPP; cg += 4) {
    const int cb = c0 + cg * 8;
    float wgt[9][8];
    #pragma unroll
    for (int t = 0; t < 9; ++t)
      #pragma unroll
      for (int j = 0; j < 8; ++j)
        wgt[t][j] = (cb + j < cmax) ? kw[t * kws + cb + j] : 0.f;

    #pragma unroll
    for (int yy = 0; yy < 4; ++yy) {
      const int ry = yg * 4 + yy;
      float acc[8] = {0.f, 0.f, 0.f, 0.f, 0.f, 0.f, 0.f, 0.f};
      #pragma unroll
      for (int dy = 0; dy < 3; ++dy)
        #pragma unroll
        for (int dx = 0; dx < 3; ++dx) {
          uint4 u = sm[cg][(ry + dy) * 18 + x + dx];
          const float* wt = wgt[dy * 3 + dx];
          acc[0] += lo16(u.x) * wt[0]; acc[1] += hi16(u.x) * wt[1];
          acc[2] += lo16(u.y) * wt[2]; acc[3] += hi16(u.y) * wt[3];
          acc[4] += lo16(u.z) * wt[4]; acc[5] += hi16(u.z) * wt[5];
          acc[6] += lo16(u.w) * wt[6]; acc[7] += hi16(u.w) * wt[7];
        }
      long po = bbase + (long)(ty0 + yg * 4 + yy) * WW + tx0 + x;
      bf16* op = out + po * ldo + cb;
      __align__(16) bf16 ov[8];
      if (MODE == 0) {
        #pragma unroll
        for (int j = 0; j < 8; ++j) ov[j] = f2b(acc[j]);
      } else if (MODE == 1) {
        #pragma unroll
        for (int j = 0; j < 8; ++j)
          ov[j] = f2b(0.5f * acc[j] * (1.f + erff(acc[j] * 0.70710678118654752440f)));
      } else {
        uint4 old = *reinterpret_cast<const uint4*>(op);
        ov[0] = f2b(lo16(old.x) * acc[0]); ov[1] = f2b(hi16(old.x) * acc[1]);
        ov[2] = f2b(lo16(old.y) * acc[2]); ov[3] = f2b(hi16(old.y) * acc[3]);
        ov[4] = f2b(lo16(old.z) * acc[4]); ov[5] = f2b(hi16(old.z) * acc[5]);
        ov[6] = f2b(lo16(old.w) * acc[6]); ov[7] = f2b(hi16(old.w) * acc[7]);
      }
      *reinterpret_cast<uint4*>(op) = *reinterpret_cast<const uint4*>(ov);
    }
  }
}

// ======== MFMA Gram + fused q/k L2 norms ========
// Grid: (256 s-chunks, 4 bh). Block: 256 thr = 4 waves; block stages 256 pixels of
// q,k transposed into LDS (row stride SP=264 elems -> 16B-aligned rows), each wave
// does 2 K=32 MFMA steps over its 64 pixels: 9 MFMA Gram(q,k) + 3 self-Gram(q,q)
// + 3 self-Gram(k,k) whose diagonals give sum q^2 / sum k^2 (the L2 norms).
// Epilogue: LDS float-atomic reduce across waves, then global atomicAdd.
__global__ __launch_bounds__(256) void gram_kernel(const bf16* __restrict__ qkv,
    float* __restrict__ G, float* __restrict__ nq, float* __restrict__ nk)
{
  constexpr int SP = 264;
  __shared__ __align__(16) char raw[2 * CH * SP * 2];   // 50688 B
  short* qs = (short*)raw;              // [48][SP]
  short* ks = qs + CH * SP;
  const int tid  = threadIdx.x;
  const int bh   = blockIdx.y;
  const int b    = bh >> 1, head = bh & 1;
  const long row0 = (long)b * HWSZ + (long)blockIdx.x * 256;
  const int lane = tid & 63;
  const int wv   = tid >> 6;
  const int m15  = lane & 15;
  const int quad = lane >> 4;

  // stage: thread = pixel, transpose into qs/ks
  {
    const short* src = (const short*)(qkv + (row0 + tid) * C3 + head * CH);
    #pragma unroll
    for (int v = 0; v < 6; ++v) {
      short8 q8 = *reinterpret_cast<const short8*>(src + v * 8);
      short8 k8 = *reinterpret_cast<const short8*>(src + CDIM + v * 8);
      #pragma unroll
      for (int j = 0; j < 8; ++j) {
        qs[(v * 8 + j) * SP + tid] = q8[j];
        ks[(v * 8 + j) * SP + tid] = k8[j];
      }
    }
  }
  __syncthreads();

  floatx4 acc[3][3], accq[3], acck[3];
  #pragma unroll
  for (int i = 0; i < 3; ++i) {
    accq[i] = (floatx4){0.f, 0.f, 0.f, 0.f};
    acck[i] = (floatx4){0.f, 0.f, 0.f, 0.f};
    #pragma unroll
    for (int j = 0; j < 3; ++j) acc[i][j] = (floatx4){0.f, 0.f, 0.f, 0.f};
  }

  #pragma unroll
  for (int kk = 0; kk < 2; ++kk) {
    const int s_off = wv * 64 + kk * 32 + quad * 8;
    short8 aq[3], bk[3];
    #pragma unroll
    for (int i = 0; i < 3; ++i) {
      aq[i] = *reinterpret_cast<const short8*>(&qs[(i * 16 + m15) * SP + s_off]);
      bk[i] = *reinterpret_cast<const short8*>(&ks[(i * 16 + m15) * SP + s_off]);
    }
    #pragma unroll
    for (int i = 0; i < 3; ++i) {
      accq[i] = __builtin_amdgcn_mfma_f32_16x16x32_bf16(aq[i], aq[i], accq[i], 0, 0, 0);
      acck[i] = __builtin_amdgcn_mfma_f32_16x16x32_bf16(bk[i], bk[i], acck[i], 0, 0, 0);
      #pragma unroll
      for (int j = 0; j < 3; ++j)
        acc[i][j] = __builtin_amdgcn_mfma_f32_16x16x32_bf16(aq[i], bk[j], acc[i][j], 0, 0, 0);
    }
  }

  // ---- reduce across waves in LDS ----
  __syncthreads();
  float* gsum = (float*)raw;            // 2304 floats
  float* nqs  = gsum + 2304;            // 48
  float* nks  = nqs + 48;               // 48
  for (int f = tid; f < 2304 + 96; f += 256) gsum[f] = 0.f;
  __syncthreads();
  const int c_lo = quad * 4;
  #pragma unroll
  for (int i = 0; i < 3; ++i)
    #pragma unroll
    for (int j = 0; j < 3; ++j)
      #pragma unroll
      for (int r = 0; r < 4; ++r)
        atomicAdd(&gsum[(i * 16 + c_lo + r) * CH + j * 16 + m15], acc[i][j][r]);
  if (m15 >= c_lo && m15 < c_lo + 4) {
    const int r = m15 - c_lo;
    #pragma unroll
    for (int i = 0; i < 3; ++i) {
      atomicAdd(&nqs[i * 16 + m15], accq[i][r]);
      atomicAdd(&nks[i * 16 + m15], acck[i][r]);
    }
  }
  __syncthreads();
  float* Gp = G + (long)bh * CH * CH;
  for (int f = tid; f < CH * CH; f += 256) atomicAdd(&Gp[f], gsum[f]);
  if (tid < CH)            atomicAdd(&nq[b * CDIM + head * CH + tid], nqs[tid]);
  else if (tid < 2 * CH)   atomicAdd(&nk[b * CDIM + head * CH + tid - CH], nks[tid - CH]);
}

// ---------------- softmax over d of G/(|q||k|)*temp ----------------
__global__ __launch_bounds__(64) void softmax_kernel(const float* __restrict__ G,
    const float* __restrict__ nq, const float* __restrict__ nk,
    const float* __restrict__ temp, float* __restrict__ attn)
{
  int r = blockIdx.x;               // 0..191 = (b*2+head)*48 + c
  int lane = threadIdx.x;
  int bh = r / CH, c = r % CH;
  int b = bh >> 1, head = bh & 1;
  float t  = temp[head];
  float qn = sqrtf(nq[b * CDIM + head * CH + c]);
  float val = 0.f, v = -INFINITY;
  if (lane < CH) {
    float kn = sqrtf(nk[b * CDIM + head * CH + lane]);
    val = G[r * CH + lane] / (qn * kn) * t;
    v = val;
  }
  float m = v;
  #pragma unroll
  for (int off = 32; off; off >>= 1) m = fmaxf(m, __shfl_xor(m, off));
  float e = (lane < CH) ? expf(val - m) : 0.f;
  float s = e;
  #pragma unroll
  for (int off = 32; off; off >>= 1) s += __shfl_xor(s, off);
  if (lane < CH) attn[r * CH + lane] = e / s;
}

// ---- o[p,c] = sum_d attn[head(c)][c%48][d] * v[p, head*48+d] ----
__global__ __launch_bounds__(256) void applyattn_kernel(const bf16* __restrict__ qkv,
    const float* __restrict__ attn, bf16* __restrict__ o)
{
  __shared__ float As[2 * CH * CH];   // 4608 f32
  __shared__ bf16  vs[64][CDIM];
  long p0 = (long)blockIdx.x * 64;
  int b = (int)(p0 >> 16);
  int tid = threadIdx.x;
  for (int f = tid; f < 2 * CH * CH; f += 256) As[f] = attn[(long)b * 2 * CH * CH + f];
  for (int f = tid; f < 64 * CDIM; f += 256) {
    int pix = f / CDIM, cc = f % CDIM;
    vs[pix][cc] = qkv[(p0 + pix) * C3 + 2 * CDIM + cc];
  }
  __syncthreads();
  for (int f = tid; f < 64 * CDIM; f += 256) {
    int pix = f / CDIM, cc = f % CDIM;
    int head = cc / CH, hc = cc % CH;
    const float* Ap = As + (head * CH + hc) * CH;
    const bf16* vp = &vs[pix][head * CH];
    float acc = 0.f;
    #pragma unroll
    for (int d = 0; d < CH; ++d) acc += Ap[d] * b2f(vp[d]);
    o[(p0 + pix) * CDIM + cc] = f2b(acc);
  }
}

extern "C" void kernel_launch(void* const* d_in, const int* in_sizes, int n_in,
                              void* d_out, int out_size, void* d_ws, size_t ws_size,
                              hipStream_t stream)
{
  const float* x          = (const float*)d_in[0];
  const float* ln1_g      = (const float*)d_in[1];
  const float* ln1_b      = (const float*)d_in[2];
  const float* ln2_g      = (const float*)d_in[3];
  const float* ln2_b      = (const float*)d_in[4];
  const float* qkv_w      = (const float*)d_in[5];
  const float* qkv_dw     = (const float*)d_in[6];
  const float* temp       = (const float*)d_in[7];
  const float* attn_out_w = (const float*)d_in[8];
  const float* ffn_in_w   = (const float*)d_in[9];
  const float* ffn_dw     = (const float*)d_in[10];
  const float* ffn_out_w  = (const float*)d_in[11];
  float* out = (float*)d_out;

  // workspace layout (peak ~168.1 MB)
  char* ws = (char*)d_ws;
  size_t off = 0;
  auto alloc = [&](size_t bytes) { void* p = ws + off; off += (bytes + 255) & ~(size_t)255; return p; };
  bf16*  BA  = (bf16*)alloc((size_t)NPIX * C3 * 2);    // qkv post-dwconv; later gelu(x1)/gated
  bf16*  BB  = (bf16*)alloc((size_t)NPIX * C3 * 2);    // qkv pre-dwconv; later t1/t2
  bf16*  BC  = (bf16*)alloc((size_t)NPIX * CDIM * 2);  // ln output / o
  float* NQ  = (float*)alloc(BATCH * CDIM * 4);
  float* NK  = (float*)alloc(BATCH * CDIM * 4);
  float* G   = (float*)alloc(BATCH * HEADS * CH * CH * 4);
  float* ATT = (float*)alloc(BATCH * HEADS * CH * CH * 4);
  hipMemsetAsync(NQ, 0, (size_t)(768 + 768 + 36864), stream);

  // ---- attention branch ----
  ln_kernel<<<NPIX / 4, 256, 0, stream>>>(x, ln1_g, ln1_b, BC);
  mfma_gemm<48, 96, false, true><<<dim3(6, NPIX / 256), 256, 0, stream>>>(
      BC, CDIM, qkv_w, C3, C3, CDIM, BB, C3, nullptr, 0);
  dwconv_tiled<C3, 48, 0><<<dim3(16, 32, 6), 256, 0, stream>>>(BB, qkv_dw, C3, C3, BA, C3);
  gram_kernel<<<dim3(256, 4), 256, 0, stream>>>(BA, G, NQ, NK);
  softmax_kernel<<<192, 64, 0, stream>>>(G, NQ, NK, temp, ATT);
  applyattn_kernel<<<NPIX / 64, 256, 0, stream>>>(BA, ATT, BC);
  mfma_gemm<48, 96, true, false><<<dim3(2, NPIX / 256), 256, 0, stream>>>(
      BC, CDIM, attn_out_w, CDIM, CDIM, CDIM, out, CDIM, x, CDIM);

  // ---- FFN branch (hidden split into two 255-col halves) ----
  ln_kernel<<<NPIX / 4, 256, 0, stream>>>(out, ln2_g, ln2_b, BC);
  mfma_gemm<64, 96, false, true><<<dim3(4, NPIX / 256), 256, 0, stream>>>(
      BC, CDIM, ffn_in_w, 2 * HIDN, HIDN, CDIM, BB, 256, nullptr, 0);
  dwconv_tiled<256, 64, 1><<<dim3(16, 32, 4), 256, 0, stream>>>(BB, ffn_dw, 2 * HIDN, HIDN, BA, 256);
  mfma_gemm<64, 96, false, true><<<dim3(4, NPIX / 256), 256, 0, stream>>>(
      BC, CDIM, ffn_in_w + HIDN, 2 * HIDN, HIDN, CDIM, BB, 256, nullptr, 0);
  dwconv_tiled<256, 64, 2><<<dim3(16, 32, 4), 256, 0, stream>>>(BB, ffn_dw + HIDN, 2 * HIDN, HIDN, BA, 256);
  mfma_gemm<48, 256, true, false><<<dim3(2, NPIX / 256), 256, 0, stream>>>(
      BA, 256, ffn_out_w, CDIM, CDIM, HIDN, out, CDIM, out, CDIM);
}

// Round 6
// 694.228 us; speedup vs baseline: 2.3388x; 1.1129x over previous
//
#include <hip/hip_runtime.h>
#include <hip/hip_bf16.h>

typedef __hip_bfloat16 bf16;
typedef __attribute__((ext_vector_type(8))) short short8;
typedef __attribute__((ext_vector_type(4))) float floatx4;

#define NPIX  131072
#define BATCH 2
#define HH    256
#define WW    256
#define CDIM  96
#define C3    288
#define HEADS 2
#define CH    48
#define HIDN  255
#define HWSZ  65536
#define EPSV  1e-5f

__device__ __forceinline__ float b2f(bf16 v) { return __bfloat162float(v); }
__device__ __forceinline__ bf16  f2b(float v) { return __float2bfloat16(v); }
__device__ __forceinline__ float lo16(unsigned u) { return __uint_as_float(u << 16); }
__device__ __forceinline__ float hi16(unsigned u) { return __uint_as_float(u & 0xffff0000u); }

// ---------------- LayerNorm: fp32 in -> bf16 out, one wave per pixel ----------------
__global__ __launch_bounds__(256) void ln_kernel(const float* __restrict__ x,
    const float* __restrict__ gamma, const float* __restrict__ beta,
    bf16* __restrict__ y)
{
  int wave = threadIdx.x >> 6;
  int lane = threadIdx.x & 63;
  long p = (long)blockIdx.x * 4 + wave;
  const float* xp = x + p * CDIM;
  float v0 = xp[lane];
  float v1 = (lane < 32) ? xp[64 + lane] : 0.f;
  float s  = v0 + v1;
  float sq = v0 * v0 + v1 * v1;
  #pragma unroll
  for (int off = 32; off; off >>= 1) {
    s  += __shfl_xor(s, off);
    sq += __shfl_xor(sq, off);
  }
  float mean = s * (1.f / 96.f);
  float var  = sq * (1.f / 96.f) - mean * mean;
  float rstd = rsqrtf(var + EPSV);
  bf16* yp = y + p * CDIM;
  yp[lane] = f2b((v0 - mean) * rstd * gamma[lane] + beta[lane]);
  if (lane < 32)
    yp[64 + lane] = f2b((v1 - mean) * rstd * gamma[64 + lane] + beta[64 + lane]);
}

// ======== MFMA GEMM: out[M,N] = A[M,KT bf16,lda] * W[KW,N fp32,ldw] (+res) ========
// wbs: per-batch W stride (batch = row/65536); 0 for shared weights.
template<int BN, int KT, bool ADD_RES, bool OUT_BF16>
__global__ __launch_bounds__(256) void mfma_gemm(
    const bf16* __restrict__ A, int lda,
    const float* __restrict__ W, int ldw, int N, int KW,
    void* __restrict__ outp, int ldo,
    const float* __restrict__ res, int ldr, long wbs)
{
  constexpr int KP = (KT % 64 == 32) ? KT : KT + 32;
  constexpr int NK = KT / 32;
  constexpr int NCT = BN / 16;
  __shared__ __align__(16) bf16 Bs[BN * KP];
  const int tid  = threadIdx.x;
  const int bn   = blockIdx.x * BN;
  const long bm  = (long)blockIdx.y * 256;
  const int lane = tid & 63;
  const int wv   = tid >> 6;
  const int m15  = lane & 15;
  const int quad = lane >> 4;

  const float* Wp = W + (bm >> 16) * wbs;
  for (int idx = tid; idx < KT * BN; idx += 256) {
    int k = idx / BN, n = idx - k * BN;
    float v = 0.f;
    if (k < KW && bn + n < N) v = Wp[(long)k * ldw + bn + n];
    Bs[n * KP + k] = f2b(v);
  }

  const bf16* Arow[4];
  #pragma unroll
  for (int rt = 0; rt < 4; ++rt)
    Arow[rt] = A + (bm + wv * 64 + rt * 16 + m15) * lda + quad * 8;

  short8 cur[4], nxt[4];
  #pragma unroll
  for (int rt = 0; rt < 4; ++rt) cur[rt] = *reinterpret_cast<const short8*>(Arow[rt]);

  __syncthreads();

  floatx4 acc[4][NCT];
  #pragma unroll
  for (int rt = 0; rt < 4; ++rt)
    #pragma unroll
    for (int ct = 0; ct < NCT; ++ct)
      acc[rt][ct] = (floatx4){0.f, 0.f, 0.f, 0.f};

  #pragma unroll
  for (int kk = 0; kk < NK; ++kk) {
    if (kk + 1 < NK) {
      #pragma unroll
      for (int rt = 0; rt < 4; ++rt)
        nxt[rt] = *reinterpret_cast<const short8*>(Arow[rt] + (kk + 1) * 32);
    }
    #pragma unroll
    for (int ct = 0; ct < NCT; ++ct) {
      short8 b = *reinterpret_cast<const short8*>(&Bs[(ct * 16 + m15) * KP + kk * 32 + quad * 8]);
      #pragma unroll
      for (int rt = 0; rt < 4; ++rt)
        acc[rt][ct] = __builtin_amdgcn_mfma_f32_16x16x32_bf16(cur[rt], b, acc[rt][ct], 0, 0, 0);
    }
    #pragma unroll
    for (int rt = 0; rt < 4; ++rt) cur[rt] = nxt[rt];
  }

  #pragma unroll
  for (int rt = 0; rt < 4; ++rt)
    #pragma unroll
    for (int ct = 0; ct < NCT; ++ct) {
      int col = bn + ct * 16 + m15;
      if (col < N) {
        #pragma unroll
        for (int r = 0; r < 4; ++r) {
          long row = bm + wv * 64 + rt * 16 + quad * 4 + r;
          float v = acc[rt][ct][r];
          if (ADD_RES) v += res[row * ldr + col];
          if (OUT_BF16) ((bf16*)outp)[row * ldo + col] = f2b(v);
          else          ((float*)outp)[row * ldo + col] = v;
        }
      }
    }
}

// ======== Spatially-tiled depthwise 3x3 conv, vectorized 8-ch I/O ========
template<int LDC, int TC, int MODE>
__global__ __launch_bounds__(256) void dwconv_tiled(
    const bf16* __restrict__ in, const float* __restrict__ kw, int kws, int cmax,
    bf16* __restrict__ out, int ldo)
{
  constexpr int VPP = TC / 8;
  __shared__ uint4 sm[VPP][18 * 18];
  const int tid = threadIdx.x;
  const int tx0 = blockIdx.x * 16;
  const int ty0 = (blockIdx.y & 15) * 16;
  const int b   = blockIdx.y >> 4;
  const int c0  = blockIdx.z * TC;
  const long bbase = (long)b * HWSZ;

  for (int f = tid; f < 18 * 18 * VPP; f += 256) {
    int pix = f / VPP;
    int v   = f - pix * VPP;
    int row = pix / 18, px = pix - row * 18;
    int y = ty0 + row - 1, x = tx0 + px - 1;
    uint4 u = make_uint4(0u, 0u, 0u, 0u);
    if ((unsigned)y < (unsigned)HH && (unsigned)x < (unsigned)WW)
      u = *reinterpret_cast<const uint4*>(in + (bbase + (long)y * WW + x) * LDC + c0 + v * 8);
    sm[v][pix] = u;
  }
  __syncthreads();

  const int x   = tid & 15;
  const int yg  = (tid >> 4) & 3;
  const int chl = tid >> 6;
  for (int cg = chl; cg < VPP; cg += 4) {
    const int cb = c0 + cg * 8;
    float wgt[9][8];
    #pragma unroll
    for (int t = 0; t < 9; ++t)
      #pragma unroll
      for (int j = 0; j < 8; ++j)
        wgt[t][j] = (cb + j < cmax) ? kw[t * kws + cb + j] : 0.f;

    #pragma unroll
    for (int yy = 0; yy < 4; ++yy) {
      const int ry = yg * 4 + yy;
      float acc[8] = {0.f, 0.f, 0.f, 0.f, 0.f, 0.f, 0.f, 0.f};
      #pragma unroll
      for (int dy = 0; dy < 3; ++dy)
        #pragma unroll
        for (int dx = 0; dx < 3; ++dx) {
          uint4 u = sm[cg][(ry + dy) * 18 + x + dx];
          const float* wt = wgt[dy * 3 + dx];
          acc[0] += lo16(u.x) * wt[0]; acc[1] += hi16(u.x) * wt[1];
          acc[2] += lo16(u.y) * wt[2]; acc[3] += hi16(u.y) * wt[3];
          acc[4] += lo16(u.z) * wt[4]; acc[5] += hi16(u.z) * wt[5];
          acc[6] += lo16(u.w) * wt[6]; acc[7] += hi16(u.w) * wt[7];
        }
      long po = bbase + (long)(ty0 + yg * 4 + yy) * WW + tx0 + x;
      bf16* op = out + po * ldo + cb;
      __align__(16) bf16 ov[8];
      if (MODE == 0) {
        #pragma unroll
        for (int j = 0; j < 8; ++j) ov[j] = f2b(acc[j]);
      } else if (MODE == 1) {
        #pragma unroll
        for (int j = 0; j < 8; ++j)
          ov[j] = f2b(0.5f * acc[j] * (1.f + erff(acc[j] * 0.70710678118654752440f)));
      } else {
        uint4 old = *reinterpret_cast<const uint4*>(op);
        ov[0] = f2b(lo16(old.x) * acc[0]); ov[1] = f2b(hi16(old.x) * acc[1]);
        ov[2] = f2b(lo16(old.y) * acc[2]); ov[3] = f2b(hi16(old.y) * acc[3]);
        ov[4] = f2b(lo16(old.z) * acc[4]); ov[5] = f2b(hi16(old.z) * acc[5]);
        ov[6] = f2b(lo16(old.w) * acc[6]); ov[7] = f2b(hi16(old.w) * acc[7]);
      }
      *reinterpret_cast<uint4*>(op) = *reinterpret_cast<const uint4*>(ov);
    }
  }
}

// ======== MFMA Gram + fused q/k L2 norms ========
__global__ __launch_bounds__(256) void gram_kernel(const bf16* __restrict__ qkv,
    float* __restrict__ G, float* __restrict__ nq, float* __restrict__ nk)
{
  constexpr int SP = 264;
  __shared__ __align__(16) char raw[2 * CH * SP * 2];   // 50688 B
  short* qs = (short*)raw;              // [48][SP]
  short* ks = qs + CH * SP;
  const int tid  = threadIdx.x;
  const int bh   = blockIdx.y;
  const int b    = bh >> 1, head = bh & 1;
  const long row0 = (long)b * HWSZ + (long)blockIdx.x * 256;
  const int lane = tid & 63;
  const int wv   = tid >> 6;
  const int m15  = lane & 15;
  const int quad = lane >> 4;

  {
    const short* src = (const short*)(qkv + (row0 + tid) * C3 + head * CH);
    #pragma unroll
    for (int v = 0; v < 6; ++v) {
      short8 q8 = *reinterpret_cast<const short8*>(src + v * 8);
      short8 k8 = *reinterpret_cast<const short8*>(src + CDIM + v * 8);
      #pragma unroll
      for (int j = 0; j < 8; ++j) {
        qs[(v * 8 + j) * SP + tid] = q8[j];
        ks[(v * 8 + j) * SP + tid] = k8[j];
      }
    }
  }
  __syncthreads();

  floatx4 acc[3][3], accq[3], acck[3];
  #pragma unroll
  for (int i = 0; i < 3; ++i) {
    accq[i] = (floatx4){0.f, 0.f, 0.f, 0.f};
    acck[i] = (floatx4){0.f, 0.f, 0.f, 0.f};
    #pragma unroll
    for (int j = 0; j < 3; ++j) acc[i][j] = (floatx4){0.f, 0.f, 0.f, 0.f};
  }

  #pragma unroll
  for (int kk = 0; kk < 2; ++kk) {
    const int s_off = wv * 64 + kk * 32 + quad * 8;
    short8 aq[3], bk[3];
    #pragma unroll
    for (int i = 0; i < 3; ++i) {
      aq[i] = *reinterpret_cast<const short8*>(&qs[(i * 16 + m15) * SP + s_off]);
      bk[i] = *reinterpret_cast<const short8*>(&ks[(i * 16 + m15) * SP + s_off]);
    }
    #pragma unroll
    for (int i = 0; i < 3; ++i) {
      accq[i] = __builtin_amdgcn_mfma_f32_16x16x32_bf16(aq[i], aq[i], accq[i], 0, 0, 0);
      acck[i] = __builtin_amdgcn_mfma_f32_16x16x32_bf16(bk[i], bk[i], acck[i], 0, 0, 0);
      #pragma unroll
      for (int j = 0; j < 3; ++j)
        acc[i][j] = __builtin_amdgcn_mfma_f32_16x16x32_bf16(aq[i], bk[j], acc[i][j], 0, 0, 0);
    }
  }

  __syncthreads();
  float* gsum = (float*)raw;            // 2304 floats
  float* nqs  = gsum + 2304;            // 48
  float* nks  = nqs + 48;               // 48
  for (int f = tid; f < 2304 + 96; f += 256) gsum[f] = 0.f;
  __syncthreads();
  const int c_lo = quad * 4;
  #pragma unroll
  for (int i = 0; i < 3; ++i)
    #pragma unroll
    for (int j = 0; j < 3; ++j)
      #pragma unroll
      for (int r = 0; r < 4; ++r)
        atomicAdd(&gsum[(i * 16 + c_lo + r) * CH + j * 16 + m15], acc[i][j][r]);
  if (m15 >= c_lo && m15 < c_lo + 4) {
    const int r = m15 - c_lo;
    #pragma unroll
    for (int i = 0; i < 3; ++i) {
      atomicAdd(&nqs[i * 16 + m15], accq[i][r]);
      atomicAdd(&nks[i * 16 + m15], acck[i][r]);
    }
  }
  __syncthreads();
  float* Gp = G + (long)bh * CH * CH;
  for (int f = tid; f < CH * CH; f += 256) atomicAdd(&Gp[f], gsum[f]);
  if (tid < CH)            atomicAdd(&nq[b * CDIM + head * CH + tid], nqs[tid]);
  else if (tid < 2 * CH)   atomicAdd(&nk[b * CDIM + head * CH + tid - CH], nks[tid - CH]);
}

// ---------------- softmax over d of G/(|q||k|)*temp ----------------
__global__ __launch_bounds__(64) void softmax_kernel(const float* __restrict__ G,
    const float* __restrict__ nq, const float* __restrict__ nk,
    const float* __restrict__ temp, float* __restrict__ attn)
{
  int r = blockIdx.x;               // 0..191 = (b*2+head)*48 + c
  int lane = threadIdx.x;
  int bh = r / CH, c = r % CH;
  int b = bh >> 1, head = bh & 1;
  float t  = temp[head];
  float qn = sqrtf(nq[b * CDIM + head * CH + c]);
  float val = 0.f, v = -INFINITY;
  if (lane < CH) {
    float kn = sqrtf(nk[b * CDIM + head * CH + lane]);
    val = G[r * CH + lane] / (qn * kn) * t;
    v = val;
  }
  float m = v;
  #pragma unroll
  for (int off = 32; off; off >>= 1) m = fmaxf(m, __shfl_xor(m, off));
  float e = (lane < CH) ? expf(val - m) : 0.f;
  float s = e;
  #pragma unroll
  for (int off = 32; off; off >>= 1) s += __shfl_xor(s, off);
  if (lane < CH) attn[r * CH + lane] = e / s;
}

// ---- M_b[k][n] = sum_cc attn[b,head(k)][cc][k%48] * aow[head(k)*48+cc][n] ----
// Folds applyattn + attn-out projection into one per-batch 96x96 matrix.
__global__ __launch_bounds__(256) void attnmat_kernel(const float* __restrict__ attn,
    const float* __restrict__ aow, float* __restrict__ M)
{
  const int b  = blockIdx.x;
  const int k0 = blockIdx.y * 16;
  for (int idx = threadIdx.x; idx < 16 * 96; idx += 256) {
    int k = k0 + idx / 96, n = idx % 96;
    int h = k / CH, kk = k % CH;
    const float* ap = attn + ((b * 2 + h) * CH) * CH + kk;  // attn[bh][cc][kk], stride CH
    const float* wp = aow + (h * CH) * CDIM + n;            // aow[h*48+cc][n], stride CDIM
    float acc = 0.f;
    #pragma unroll
    for (int cc = 0; cc < CH; ++cc) acc += ap[cc * CH] * wp[cc * CDIM];
    M[(long)b * CDIM * CDIM + k * CDIM + n] = acc;
  }
}

extern "C" void kernel_launch(void* const* d_in, const int* in_sizes, int n_in,
                              void* d_out, int out_size, void* d_ws, size_t ws_size,
                              hipStream_t stream)
{
  const float* x          = (const float*)d_in[0];
  const float* ln1_g      = (const float*)d_in[1];
  const float* ln1_b      = (const float*)d_in[2];
  const float* ln2_g      = (const float*)d_in[3];
  const float* ln2_b      = (const float*)d_in[4];
  const float* qkv_w      = (const float*)d_in[5];
  const float* qkv_dw     = (const float*)d_in[6];
  const float* temp       = (const float*)d_in[7];
  const float* attn_out_w = (const float*)d_in[8];
  const float* ffn_in_w   = (const float*)d_in[9];
  const float* ffn_dw     = (const float*)d_in[10];
  const float* ffn_out_w  = (const float*)d_in[11];
  float* out = (float*)d_out;

  // workspace layout (peak ~168.2 MB)
  char* ws = (char*)d_ws;
  size_t off = 0;
  auto alloc = [&](size_t bytes) { void* p = ws + off; off += (bytes + 255) & ~(size_t)255; return p; };
  bf16*  BA  = (bf16*)alloc((size_t)NPIX * C3 * 2);    // qkv post-dwconv; later gelu(x1)/gated
  bf16*  BB  = (bf16*)alloc((size_t)NPIX * C3 * 2);    // qkv pre-dwconv; later t1/t2
  bf16*  BC  = (bf16*)alloc((size_t)NPIX * CDIM * 2);  // ln outputs
  float* NQ  = (float*)alloc(BATCH * CDIM * 4);
  float* NK  = (float*)alloc(BATCH * CDIM * 4);
  float* G   = (float*)alloc(BATCH * HEADS * CH * CH * 4);
  float* ATT = (float*)alloc(BATCH * HEADS * CH * CH * 4);
  float* AM  = (float*)alloc(BATCH * CDIM * CDIM * 4); // fused attn matrices
  hipMemsetAsync(NQ, 0, (size_t)(768 + 768 + 36864), stream);

  // ---- attention branch ----
  ln_kernel<<<NPIX / 4, 256, 0, stream>>>(x, ln1_g, ln1_b, BC);
  mfma_gemm<48, 96, false, true><<<dim3(6, NPIX / 256), 256, 0, stream>>>(
      BC, CDIM, qkv_w, C3, C3, CDIM, BB, C3, nullptr, 0, 0);
  dwconv_tiled<C3, 48, 0><<<dim3(16, 32, 6), 256, 0, stream>>>(BB, qkv_dw, C3, C3, BA, C3);
  gram_kernel<<<dim3(256, 4), 256, 0, stream>>>(BA, G, NQ, NK);
  softmax_kernel<<<192, 64, 0, stream>>>(G, NQ, NK, temp, ATT);
  attnmat_kernel<<<dim3(2, 6), 256, 0, stream>>>(ATT, attn_out_w, AM);
  // out = x + v @ M_b   (v = qkv cols 192..287)
  mfma_gemm<48, 96, true, false><<<dim3(2, NPIX / 256), 256, 0, stream>>>(
      BA + 2 * CDIM, C3, AM, CDIM, CDIM, CDIM, out, CDIM, x, CDIM, (long)CDIM * CDIM);

  // ---- FFN branch (hidden split into two 255-col halves) ----
  ln_kernel<<<NPIX / 4, 256, 0, stream>>>(out, ln2_g, ln2_b, BC);
  mfma_gemm<64, 96, false, true><<<dim3(4, NPIX / 256), 256, 0, stream>>>(
      BC, CDIM, ffn_in_w, 2 * HIDN, HIDN, CDIM, BB, 256, nullptr, 0, 0);
  dwconv_tiled<256, 64, 1><<<dim3(16, 32, 4), 256, 0, stream>>>(BB, ffn_dw, 2 * HIDN, HIDN, BA, 256);
  mfma_gemm<64, 96, false, true><<<dim3(4, NPIX / 256), 256, 0, stream>>>(
      BC, CDIM, ffn_in_w + HIDN, 2 * HIDN, HIDN, CDIM, BB, 256, nullptr, 0, 0);
  dwconv_tiled<256, 64, 2><<<dim3(16, 32, 4), 256, 0, stream>>>(BB, ffn_dw + HIDN, 2 * HIDN, HIDN, BA, 256);
  mfma_gemm<48, 256, true, false><<<dim3(2, NPIX / 256), 256, 0, stream>>>(
      BA, 256, ffn_out_w, CDIM, CDIM, HIDN, out, CDIM, out, CDIM, 0);
}

// Round 7
// 667.667 us; speedup vs baseline: 2.4319x; 1.0398x over previous
//
#include <hip/hip_runtime.h>
#include <hip/hip_bf16.h>

typedef __hip_bfloat16 bf16;
typedef __attribute__((ext_vector_type(8))) short short8;
typedef __attribute__((ext_vector_type(4))) float floatx4;

#define NPIX  131072
#define BATCH 2
#define HH    256
#define WW    256
#define CDIM  96
#define C3    288
#define HEADS 2
#define CH    48
#define HIDN  255
#define HWSZ  65536
#define EPSV  1e-5f

__device__ __forceinline__ float b2f(bf16 v) { return __bfloat162float(v); }
__device__ __forceinline__ bf16  f2b(float v) { return __float2bfloat16(v); }
__device__ __forceinline__ float lo16(unsigned u) { return __uint_as_float(u << 16); }
__device__ __forceinline__ float hi16(unsigned u) { return __uint_as_float(u & 0xffff0000u); }

// ---------------- LayerNorm: fp32 in -> bf16 out, one wave per pixel ----------------
__global__ __launch_bounds__(256) void ln_kernel(const float* __restrict__ x,
    const float* __restrict__ gamma, const float* __restrict__ beta,
    bf16* __restrict__ y)
{
  int wave = threadIdx.x >> 6;
  int lane = threadIdx.x & 63;
  long p = (long)blockIdx.x * 4 + wave;
  const float* xp = x + p * CDIM;
  float v0 = xp[lane];
  float v1 = (lane < 32) ? xp[64 + lane] : 0.f;
  float s  = v0 + v1;
  float sq = v0 * v0 + v1 * v1;
  #pragma unroll
  for (int off = 32; off; off >>= 1) {
    s  += __shfl_xor(s, off);
    sq += __shfl_xor(sq, off);
  }
  float mean = s * (1.f / 96.f);
  float var  = sq * (1.f / 96.f) - mean * mean;
  float rstd = rsqrtf(var + EPSV);
  bf16* yp = y + p * CDIM;
  yp[lane] = f2b((v0 - mean) * rstd * gamma[lane] + beta[lane]);
  if (lane < 32)
    yp[64 + lane] = f2b((v1 - mean) * rstd * gamma[64 + lane] + beta[64 + lane]);
}

// ======== MFMA GEMM: out[M,N] = A[M,KT bf16,lda] * W[KW,N fp32,ldw] (+res) ========
// BM rows/block (4 waves, each RT=BM/64 16-row tiles); wbs = per-batch W stride.
// Bs row stride KP: KP/2 % 32 == 4 dwords -> conflict-free ds_read_b128 across n-lanes.
template<int BM, int BN, int KT, bool ADD_RES, bool OUT_BF16>
__global__ __launch_bounds__(256) void mfma_gemm(
    const bf16* __restrict__ A, int lda,
    const float* __restrict__ W, int ldw, int N, int KW,
    void* __restrict__ outp, int ldo,
    const float* __restrict__ res, int ldr, long wbs)
{
  constexpr int KPD = KT / 2 + ((4 - KT / 2) % 32 + 32) % 32;  // dwords, ==4 mod 32
  constexpr int KP  = 2 * KPD;
  constexpr int NK  = KT / 32;
  constexpr int NCT = BN / 16;
  constexpr int RT  = BM / 64;                // 16-row tiles per wave
  __shared__ __align__(16) bf16 Bs[BN * KP];
  const int tid  = threadIdx.x;
  const int bn   = blockIdx.x * BN;
  const long bm  = (long)blockIdx.y * BM;
  const int lane = tid & 63;
  const int wv   = tid >> 6;
  const int m15  = lane & 15;
  const int quad = lane >> 4;

  const float* Wp = W + (bm >> 16) * wbs;
  for (int idx = tid; idx < KT * BN; idx += 256) {
    int k = idx / BN, n = idx - k * BN;
    float v = 0.f;
    if (k < KW && bn + n < N) v = Wp[(long)k * ldw + bn + n];
    Bs[n * KP + k] = f2b(v);
  }

  const bf16* Arow[RT];
  #pragma unroll
  for (int rt = 0; rt < RT; ++rt)
    Arow[rt] = A + (bm + wv * (BM / 4) + rt * 16 + m15) * lda + quad * 8;

  short8 cur[RT], nxt[RT];
  #pragma unroll
  for (int rt = 0; rt < RT; ++rt) cur[rt] = *reinterpret_cast<const short8*>(Arow[rt]);

  __syncthreads();

  floatx4 acc[RT][NCT];
  #pragma unroll
  for (int rt = 0; rt < RT; ++rt)
    #pragma unroll
    for (int ct = 0; ct < NCT; ++ct)
      acc[rt][ct] = (floatx4){0.f, 0.f, 0.f, 0.f};

  #pragma unroll
  for (int kk = 0; kk < NK; ++kk) {
    if (kk + 1 < NK) {
      #pragma unroll
      for (int rt = 0; rt < RT; ++rt)
        nxt[rt] = *reinterpret_cast<const short8*>(Arow[rt] + (kk + 1) * 32);
    }
    #pragma unroll
    for (int ct = 0; ct < NCT; ++ct) {
      short8 b = *reinterpret_cast<const short8*>(&Bs[(ct * 16 + m15) * KP + kk * 32 + quad * 8]);
      #pragma unroll
      for (int rt = 0; rt < RT; ++rt)
        acc[rt][ct] = __builtin_amdgcn_mfma_f32_16x16x32_bf16(cur[rt], b, acc[rt][ct], 0, 0, 0);
    }
    #pragma unroll
    for (int rt = 0; rt < RT; ++rt) cur[rt] = nxt[rt];
  }

  #pragma unroll
  for (int rt = 0; rt < RT; ++rt)
    #pragma unroll
    for (int ct = 0; ct < NCT; ++ct) {
      int col = bn + ct * 16 + m15;
      if (col < N) {
        #pragma unroll
        for (int r = 0; r < 4; ++r) {
          long row = bm + wv * (BM / 4) + rt * 16 + quad * 4 + r;
          float v = acc[rt][ct][r];
          if (ADD_RES) v += res[row * ldr + col];
          if (OUT_BF16) ((bf16*)outp)[row * ldo + col] = f2b(v);
          else          ((float*)outp)[row * ldo + col] = v;
        }
      }
    }
}

// ======== Spatially-tiled depthwise 3x3 conv, vectorized 8-ch I/O ========
template<int LDC, int TC, int MODE>
__global__ __launch_bounds__(256) void dwconv_tiled(
    const bf16* __restrict__ in, const float* __restrict__ kw, int kws, int cmax,
    bf16* __restrict__ out, int ldo)
{
  constexpr int VPP = TC / 8;
  __shared__ uint4 sm[VPP][18 * 18];
  const int tid = threadIdx.x;
  const int tx0 = blockIdx.x * 16;
  const int ty0 = (blockIdx.y & 15) * 16;
  const int b   = blockIdx.y >> 4;
  const int c0  = blockIdx.z * TC;
  const long bbase = (long)b * HWSZ;

  for (int f = tid; f < 18 * 18 * VPP; f += 256) {
    int pix = f / VPP;
    int v   = f - pix * VPP;
    int row = pix / 18, px = pix - row * 18;
    int y = ty0 + row - 1, x = tx0 + px - 1;
    uint4 u = make_uint4(0u, 0u, 0u, 0u);
    if ((unsigned)y < (unsigned)HH && (unsigned)x < (unsigned)WW)
      u = *reinterpret_cast<const uint4*>(in + (bbase + (long)y * WW + x) * LDC + c0 + v * 8);
    sm[v][pix] = u;
  }
  __syncthreads();

  const int x   = tid & 15;
  const int yg  = (tid >> 4) & 3;
  const int chl = tid >> 6;
  for (int cg = chl; cg < VPP; cg += 4) {
    const int cb = c0 + cg * 8;
    float wgt[9][8];
    #pragma unroll
    for (int t = 0; t < 9; ++t)
      #pragma unroll
      for (int j = 0; j < 8; ++j)
        wgt[t][j] = (cb + j < cmax) ? kw[t * kws + cb + j] : 0.f;

    #pragma unroll
    for (int yy = 0; yy < 4; ++yy) {
      const int ry = yg * 4 + yy;
      float acc[8] = {0.f, 0.f, 0.f, 0.f, 0.f, 0.f, 0.f, 0.f};
      #pragma unroll
      for (int dy = 0; dy < 3; ++dy)
        #pragma unroll
        for (int dx = 0; dx < 3; ++dx) {
          uint4 u = sm[cg][(ry + dy) * 18 + x + dx];
          const float* wt = wgt[dy * 3 + dx];
          acc[0] += lo16(u.x) * wt[0]; acc[1] += hi16(u.x) * wt[1];
          acc[2] += lo16(u.y) * wt[2]; acc[3] += hi16(u.y) * wt[3];
          acc[4] += lo16(u.z) * wt[4]; acc[5] += hi16(u.z) * wt[5];
          acc[6] += lo16(u.w) * wt[6]; acc[7] += hi16(u.w) * wt[7];
        }
      long po = bbase + (long)(ty0 + yg * 4 + yy) * WW + tx0 + x;
      bf16* op = out + po * ldo + cb;
      __align__(16) bf16 ov[8];
      if (MODE == 0) {
        #pragma unroll
        for (int j = 0; j < 8; ++j) ov[j] = f2b(acc[j]);
      } else if (MODE == 1) {
        #pragma unroll
        for (int j = 0; j < 8; ++j)
          ov[j] = f2b(0.5f * acc[j] * (1.f + erff(acc[j] * 0.70710678118654752440f)));
      } else {
        uint4 old = *reinterpret_cast<const uint4*>(op);
        ov[0] = f2b(lo16(old.x) * acc[0]); ov[1] = f2b(hi16(old.x) * acc[1]);
        ov[2] = f2b(lo16(old.y) * acc[2]); ov[3] = f2b(hi16(old.y) * acc[3]);
        ov[4] = f2b(lo16(old.z) * acc[4]); ov[5] = f2b(hi16(old.z) * acc[5]);
        ov[6] = f2b(lo16(old.w) * acc[6]); ov[7] = f2b(hi16(old.w) * acc[7]);
      }
      *reinterpret_cast<uint4*>(op) = *reinterpret_cast<const uint4*>(ov);
    }
  }
}

// ======== MFMA Gram + fused q/k L2 norms ========
__global__ __launch_bounds__(256) void gram_kernel(const bf16* __restrict__ qkv,
    float* __restrict__ G, float* __restrict__ nq, float* __restrict__ nk)
{
  constexpr int SP = 264;
  __shared__ __align__(16) char raw[2 * CH * SP * 2];   // 50688 B
  short* qs = (short*)raw;              // [48][SP]
  short* ks = qs + CH * SP;
  const int tid  = threadIdx.x;
  const int bh   = blockIdx.y;
  const int b    = bh >> 1, head = bh & 1;
  const long row0 = (long)b * HWSZ + (long)blockIdx.x * 256;
  const int lane = tid & 63;
  const int wv   = tid >> 6;
  const int m15  = lane & 15;
  const int quad = lane >> 4;

  {
    const short* src = (const short*)(qkv + (row0 + tid) * C3 + head * CH);
    #pragma unroll
    for (int v = 0; v < 6; ++v) {
      short8 q8 = *reinterpret_cast<const short8*>(src + v * 8);
      short8 k8 = *reinterpret_cast<const short8*>(src + CDIM + v * 8);
      #pragma unroll
      for (int j = 0; j < 8; ++j) {
        qs[(v * 8 + j) * SP + tid] = q8[j];
        ks[(v * 8 + j) * SP + tid] = k8[j];
      }
    }
  }
  __syncthreads();

  floatx4 acc[3][3], accq[3], acck[3];
  #pragma unroll
  for (int i = 0; i < 3; ++i) {
    accq[i] = (floatx4){0.f, 0.f, 0.f, 0.f};
    acck[i] = (floatx4){0.f, 0.f, 0.f, 0.f};
    #pragma unroll
    for (int j = 0; j < 3; ++j) acc[i][j] = (floatx4){0.f, 0.f, 0.f, 0.f};
  }

  #pragma unroll
  for (int kk = 0; kk < 2; ++kk) {
    const int s_off = wv * 64 + kk * 32 + quad * 8;
    short8 aq[3], bk[3];
    #pragma unroll
    for (int i = 0; i < 3; ++i) {
      aq[i] = *reinterpret_cast<const short8*>(&qs[(i * 16 + m15) * SP + s_off]);
      bk[i] = *reinterpret_cast<const short8*>(&ks[(i * 16 + m15) * SP + s_off]);
    }
    #pragma unroll
    for (int i = 0; i < 3; ++i) {
      accq[i] = __builtin_amdgcn_mfma_f32_16x16x32_bf16(aq[i], aq[i], accq[i], 0, 0, 0);
      acck[i] = __builtin_amdgcn_mfma_f32_16x16x32_bf16(bk[i], bk[i], acck[i], 0, 0, 0);
      #pragma unroll
      for (int j = 0; j < 3; ++j)
        acc[i][j] = __builtin_amdgcn_mfma_f32_16x16x32_bf16(aq[i], bk[j], acc[i][j], 0, 0, 0);
    }
  }

  __syncthreads();
  float* gsum = (float*)raw;            // 2304 floats
  float* nqs  = gsum + 2304;            // 48
  float* nks  = nqs + 48;               // 48
  for (int f = tid; f < 2304 + 96; f += 256) gsum[f] = 0.f;
  __syncthreads();
  const int c_lo = quad * 4;
  #pragma unroll
  for (int i = 0; i < 3; ++i)
    #pragma unroll
    for (int j = 0; j < 3; ++j)
      #pragma unroll
      for (int r = 0; r < 4; ++r)
        atomicAdd(&gsum[(i * 16 + c_lo + r) * CH + j * 16 + m15], acc[i][j][r]);
  if (m15 >= c_lo && m15 < c_lo + 4) {
    const int r = m15 - c_lo;
    #pragma unroll
    for (int i = 0; i < 3; ++i) {
      atomicAdd(&nqs[i * 16 + m15], accq[i][r]);
      atomicAdd(&nks[i * 16 + m15], acck[i][r]);
    }
  }
  __syncthreads();
  float* Gp = G + (long)bh * CH * CH;
  for (int f = tid; f < CH * CH; f += 256) atomicAdd(&Gp[f], gsum[f]);
  if (tid < CH)            atomicAdd(&nq[b * CDIM + head * CH + tid], nqs[tid]);
  else if (tid < 2 * CH)   atomicAdd(&nk[b * CDIM + head * CH + tid - CH], nks[tid - CH]);
}

// ---------------- softmax over d of G/(|q||k|)*temp ----------------
__global__ __launch_bounds__(64) void softmax_kernel(const float* __restrict__ G,
    const float* __restrict__ nq, const float* __restrict__ nk,
    const float* __restrict__ temp, float* __restrict__ attn)
{
  int r = blockIdx.x;               // 0..191 = (b*2+head)*48 + c
  int lane = threadIdx.x;
  int bh = r / CH, c = r % CH;
  int b = bh >> 1, head = bh & 1;
  float t  = temp[head];
  float qn = sqrtf(nq[b * CDIM + head * CH + c]);
  float val = 0.f, v = -INFINITY;
  if (lane < CH) {
    float kn = sqrtf(nk[b * CDIM + head * CH + lane]);
    val = G[r * CH + lane] / (qn * kn) * t;
    v = val;
  }
  float m = v;
  #pragma unroll
  for (int off = 32; off; off >>= 1) m = fmaxf(m, __shfl_xor(m, off));
  float e = (lane < CH) ? expf(val - m) : 0.f;
  float s = e;
  #pragma unroll
  for (int off = 32; off; off >>= 1) s += __shfl_xor(s, off);
  if (lane < CH) attn[r * CH + lane] = e / s;
}

// ---- M_b[k][n] = sum_cc attn[b,head(k)][cc][k%48] * aow[head(k)*48+cc][n] ----
__global__ __launch_bounds__(256) void attnmat_kernel(const float* __restrict__ attn,
    const float* __restrict__ aow, float* __restrict__ M)
{
  const int b  = blockIdx.x;
  const int k0 = blockIdx.y * 16;
  for (int idx = threadIdx.x; idx < 16 * 96; idx += 256) {
    int k = k0 + idx / 96, n = idx % 96;
    int h = k / CH, kk = k % CH;
    const float* ap = attn + ((b * 2 + h) * CH) * CH + kk;  // attn[bh][cc][kk], stride CH
    const float* wp = aow + (h * CH) * CDIM + n;            // aow[h*48+cc][n], stride CDIM
    float acc = 0.f;
    #pragma unroll
    for (int cc = 0; cc < CH; ++cc) acc += ap[cc * CH] * wp[cc * CDIM];
    M[(long)b * CDIM * CDIM + k * CDIM + n] = acc;
  }
}

extern "C" void kernel_launch(void* const* d_in, const int* in_sizes, int n_in,
                              void* d_out, int out_size, void* d_ws, size_t ws_size,
                              hipStream_t stream)
{
  const float* x          = (const float*)d_in[0];
  const float* ln1_g      = (const float*)d_in[1];
  const float* ln1_b      = (const float*)d_in[2];
  const float* ln2_g      = (const float*)d_in[3];
  const float* ln2_b      = (const float*)d_in[4];
  const float* qkv_w      = (const float*)d_in[5];
  const float* qkv_dw     = (const float*)d_in[6];
  const float* temp       = (const float*)d_in[7];
  const float* attn_out_w = (const float*)d_in[8];
  const float* ffn_in_w   = (const float*)d_in[9];
  const float* ffn_dw     = (const float*)d_in[10];
  const float* ffn_out_w  = (const float*)d_in[11];
  float* out = (float*)d_out;

  // workspace layout (peak ~168.2 MB)
  char* ws = (char*)d_ws;
  size_t off = 0;
  auto alloc = [&](size_t bytes) { void* p = ws + off; off += (bytes + 255) & ~(size_t)255; return p; };
  bf16*  BA  = (bf16*)alloc((size_t)NPIX * C3 * 2);    // qkv post-dwconv; later gelu(x1)/gated
  bf16*  BB  = (bf16*)alloc((size_t)NPIX * C3 * 2);    // qkv pre-dwconv; later t1/t2
  bf16*  BC  = (bf16*)alloc((size_t)NPIX * CDIM * 2);  // ln outputs
  float* NQ  = (float*)alloc(BATCH * CDIM * 4);
  float* NK  = (float*)alloc(BATCH * CDIM * 4);
  float* G   = (float*)alloc(BATCH * HEADS * CH * CH * 4);
  float* ATT = (float*)alloc(BATCH * HEADS * CH * CH * 4);
  float* AM  = (float*)alloc(BATCH * CDIM * CDIM * 4); // fused attn matrices
  hipMemsetAsync(NQ, 0, (size_t)(768 + 768 + 36864), stream);

  // ---- attention branch ----
  ln_kernel<<<NPIX / 4, 256, 0, stream>>>(x, ln1_g, ln1_b, BC);
  mfma_gemm<128, 48, 96, false, true><<<dim3(6, NPIX / 128), 256, 0, stream>>>(
      BC, CDIM, qkv_w, C3, C3, CDIM, BB, C3, nullptr, 0, 0);
  dwconv_tiled<C3, 48, 0><<<dim3(16, 32, 6), 256, 0, stream>>>(BB, qkv_dw, C3, C3, BA, C3);
  gram_kernel<<<dim3(256, 4), 256, 0, stream>>>(BA, G, NQ, NK);
  softmax_kernel<<<192, 64, 0, stream>>>(G, NQ, NK, temp, ATT);
  attnmat_kernel<<<dim3(2, 6), 256, 0, stream>>>(ATT, attn_out_w, AM);
  // out = x + v @ M_b   (v = qkv cols 192..287)
  mfma_gemm<128, 48, 96, true, false><<<dim3(2, NPIX / 128), 256, 0, stream>>>(
      BA + 2 * CDIM, C3, AM, CDIM, CDIM, CDIM, out, CDIM, x, CDIM, (long)CDIM * CDIM);

  // ---- FFN branch (hidden split into two 255-col halves) ----
  ln_kernel<<<NPIX / 4, 256, 0, stream>>>(out, ln2_g, ln2_b, BC);
  mfma_gemm<128, 64, 96, false, true><<<dim3(4, NPIX / 128), 256, 0, stream>>>(
      BC, CDIM, ffn_in_w, 2 * HIDN, HIDN, CDIM, BB, 256, nullptr, 0, 0);
  dwconv_tiled<256, 64, 1><<<dim3(16, 32, 4), 256, 0, stream>>>(BB, ffn_dw, 2 * HIDN, HIDN, BA, 256);
  mfma_gemm<128, 64, 96, false, true><<<dim3(4, NPIX / 128), 256, 0, stream>>>(
      BC, CDIM, ffn_in_w + HIDN, 2 * HIDN, HIDN, CDIM, BB, 256, nullptr, 0, 0);
  dwconv_tiled<256, 64, 2><<<dim3(16, 32, 4), 256, 0, stream>>>(BB, ffn_dw + HIDN, 2 * HIDN, HIDN, BA, 256);
  mfma_gemm<128, 48, 256, true, false><<<dim3(2, NPIX / 128), 256, 0, stream>>>(
      BA, 256, ffn_out_w, CDIM, CDIM, HIDN, out, CDIM, out, CDIM, 0);
}

// Round 8
// 649.046 us; speedup vs baseline: 2.5016x; 1.0287x over previous
//
#include <hip/hip_runtime.h>
#include <hip/hip_bf16.h>

typedef __hip_bfloat16 bf16;
typedef __attribute__((ext_vector_type(8))) short short8;
typedef __attribute__((ext_vector_type(4))) float floatx4;

#define NPIX  131072
#define BATCH 2
#define HH    256
#define WW    256
#define CDIM  96
#define C3    288
#define HEADS 2
#define CH    48
#define HIDN  255
#define HWSZ  65536
#define EPSV  1e-5f

__device__ __forceinline__ float b2f(bf16 v) { return __bfloat162float(v); }
__device__ __forceinline__ bf16  f2b(float v) { return __float2bfloat16(v); }
__device__ __forceinline__ short f2bs(float v) { bf16 h = __float2bfloat16(v); return *reinterpret_cast<short*>(&h); }
__device__ __forceinline__ float lo16(unsigned u) { return __uint_as_float(u << 16); }
__device__ __forceinline__ float hi16(unsigned u) { return __uint_as_float(u & 0xffff0000u); }

// ======== Generic MFMA GEMM, deep A-prefetch ========
// out[M,N] = A[M,KT bf16,lda] * W[KW,N fp32,ldw] (+res). BM rows/block, 4 waves.
// All RT*NK A-fragments loaded up-front (graduated vmcnt waits by compiler).
template<int BM, int BN, int KT, bool ADD_RES, bool OUT_BF16>
__global__ __launch_bounds__(256) void mfma_gemm(
    const bf16* __restrict__ A, int lda,
    const float* __restrict__ W, int ldw, int N, int KW,
    void* __restrict__ outp, int ldo,
    const float* __restrict__ res, int ldr, long wbs)
{
  constexpr int KPD = KT / 2 + ((4 - KT / 2) % 32 + 32) % 32;  // dwords, ==4 mod 32
  constexpr int KP  = 2 * KPD;
  constexpr int NK  = KT / 32;
  constexpr int NCT = BN / 16;
  constexpr int RT  = BM / 64;
  __shared__ __align__(16) bf16 Bs[BN * KP];
  const int tid  = threadIdx.x;
  const int bn   = blockIdx.x * BN;
  const long bm  = (long)blockIdx.y * BM;
  const int lane = tid & 63;
  const int wv   = tid >> 6;
  const int m15  = lane & 15;
  const int quad = lane >> 4;

  const float* Wp = W + (bm >> 16) * wbs;
  for (int idx = tid; idx < KT * BN; idx += 256) {
    int k = idx / BN, n = idx - k * BN;
    float v = 0.f;
    if (k < KW && bn + n < N) v = Wp[(long)k * ldw + bn + n];
    Bs[n * KP + k] = f2b(v);
  }

  short8 areg[RT][NK];
  #pragma unroll
  for (int rt = 0; rt < RT; ++rt) {
    const bf16* ap = A + (bm + wv * (BM / 4) + rt * 16 + m15) * lda + quad * 8;
    #pragma unroll
    for (int kk = 0; kk < NK; ++kk)
      areg[rt][kk] = *reinterpret_cast<const short8*>(ap + kk * 32);
  }

  __syncthreads();

  floatx4 acc[RT][NCT];
  #pragma unroll
  for (int rt = 0; rt < RT; ++rt)
    #pragma unroll
    for (int ct = 0; ct < NCT; ++ct)
      acc[rt][ct] = (floatx4){0.f, 0.f, 0.f, 0.f};

  #pragma unroll
  for (int kk = 0; kk < NK; ++kk)
    #pragma unroll
    for (int ct = 0; ct < NCT; ++ct) {
      short8 b = *reinterpret_cast<const short8*>(&Bs[(ct * 16 + m15) * KP + kk * 32 + quad * 8]);
      #pragma unroll
      for (int rt = 0; rt < RT; ++rt)
        acc[rt][ct] = __builtin_amdgcn_mfma_f32_16x16x32_bf16(areg[rt][kk], b, acc[rt][ct], 0, 0, 0);
    }

  #pragma unroll
  for (int rt = 0; rt < RT; ++rt)
    #pragma unroll
    for (int ct = 0; ct < NCT; ++ct) {
      int col = bn + ct * 16 + m15;
      if (col < N) {
        #pragma unroll
        for (int r = 0; r < 4; ++r) {
          long row = bm + wv * (BM / 4) + rt * 16 + quad * 4 + r;
          float v = acc[rt][ct][r];
          if (ADD_RES) v += res[row * ldr + col];
          if (OUT_BF16) ((bf16*)outp)[row * ldo + col] = f2b(v);
          else          ((float*)outp)[row * ldo + col] = v;
        }
      }
    }
}

// ======== qkv GEMM with fused LayerNorm on A ========
// A = x fp32 [M,96]; LN per row (biased var, eps) then bf16 fragments; W fp32.
template<int BM, int BN>
__global__ __launch_bounds__(256) void mfma_gemm_lnA(
    const float* __restrict__ X, const float* __restrict__ gam, const float* __restrict__ bet,
    const float* __restrict__ W, int ldw, int N,
    bf16* __restrict__ outp, int ldo)
{
  constexpr int KP  = 136;   // 68 dwords == 4 mod 32
  constexpr int NCT = BN / 16;
  constexpr int RT  = BM / 64;
  __shared__ __align__(16) bf16 Bs[BN * KP];
  const int tid  = threadIdx.x;
  const int bn   = blockIdx.x * BN;
  const long bm  = (long)blockIdx.y * BM;
  const int lane = tid & 63;
  const int wv   = tid >> 6;
  const int m15  = lane & 15;
  const int quad = lane >> 4;

  for (int idx = tid; idx < 96 * BN; idx += 256) {
    int k = idx / BN, n = idx - k * BN;
    float v = (bn + n < N) ? W[(long)k * ldw + bn + n] : 0.f;
    Bs[n * KP + k] = f2b(v);
  }

  // load x rows (fp32), all 3 k-slices
  float xv[RT][24];
  #pragma unroll
  for (int rt = 0; rt < RT; ++rt) {
    const float* xp = X + (bm + wv * (BM / 4) + rt * 16 + m15) * CDIM + quad * 8;
    #pragma unroll
    for (int kk = 0; kk < 3; ++kk) {
      float4 t0 = *reinterpret_cast<const float4*>(xp + kk * 32);
      float4 t1 = *reinterpret_cast<const float4*>(xp + kk * 32 + 4);
      xv[rt][kk * 8 + 0] = t0.x; xv[rt][kk * 8 + 1] = t0.y; xv[rt][kk * 8 + 2] = t0.z; xv[rt][kk * 8 + 3] = t0.w;
      xv[rt][kk * 8 + 4] = t1.x; xv[rt][kk * 8 + 5] = t1.y; xv[rt][kk * 8 + 6] = t1.z; xv[rt][kk * 8 + 7] = t1.w;
    }
  }
  // gamma/beta for this lane's k positions
  float gv[24], bv[24];
  #pragma unroll
  for (int kk = 0; kk < 3; ++kk) {
    float4 g0 = *reinterpret_cast<const float4*>(gam + kk * 32 + quad * 8);
    float4 g1 = *reinterpret_cast<const float4*>(gam + kk * 32 + quad * 8 + 4);
    float4 b0 = *reinterpret_cast<const float4*>(bet + kk * 32 + quad * 8);
    float4 b1 = *reinterpret_cast<const float4*>(bet + kk * 32 + quad * 8 + 4);
    gv[kk * 8 + 0] = g0.x; gv[kk * 8 + 1] = g0.y; gv[kk * 8 + 2] = g0.z; gv[kk * 8 + 3] = g0.w;
    gv[kk * 8 + 4] = g1.x; gv[kk * 8 + 5] = g1.y; gv[kk * 8 + 6] = g1.z; gv[kk * 8 + 7] = g1.w;
    bv[kk * 8 + 0] = b0.x; bv[kk * 8 + 1] = b0.y; bv[kk * 8 + 2] = b0.z; bv[kk * 8 + 3] = b0.w;
    bv[kk * 8 + 4] = b1.x; bv[kk * 8 + 5] = b1.y; bv[kk * 8 + 6] = b1.z; bv[kk * 8 + 7] = b1.w;
  }

  short8 areg[RT][3];
  #pragma unroll
  for (int rt = 0; rt < RT; ++rt) {
    float s = 0.f, sq = 0.f;
    #pragma unroll
    for (int e = 0; e < 24; ++e) { s += xv[rt][e]; sq += xv[rt][e] * xv[rt][e]; }
    s  += __shfl_xor(s, 16);  s  += __shfl_xor(s, 32);
    sq += __shfl_xor(sq, 16); sq += __shfl_xor(sq, 32);
    float mean = s * (1.f / 96.f);
    float var  = sq * (1.f / 96.f) - mean * mean;
    float rstd = rsqrtf(var + EPSV);
    #pragma unroll
    for (int kk = 0; kk < 3; ++kk)
      #pragma unroll
      for (int j = 0; j < 8; ++j)
        areg[rt][kk][j] = f2bs((xv[rt][kk * 8 + j] - mean) * rstd * gv[kk * 8 + j] + bv[kk * 8 + j]);
  }

  __syncthreads();

  floatx4 acc[RT][NCT];
  #pragma unroll
  for (int rt = 0; rt < RT; ++rt)
    #pragma unroll
    for (int ct = 0; ct < NCT; ++ct)
      acc[rt][ct] = (floatx4){0.f, 0.f, 0.f, 0.f};

  #pragma unroll
  for (int kk = 0; kk < 3; ++kk)
    #pragma unroll
    for (int ct = 0; ct < NCT; ++ct) {
      short8 b = *reinterpret_cast<const short8*>(&Bs[(ct * 16 + m15) * KP + kk * 32 + quad * 8]);
      #pragma unroll
      for (int rt = 0; rt < RT; ++rt)
        acc[rt][ct] = __builtin_amdgcn_mfma_f32_16x16x32_bf16(areg[rt][kk], b, acc[rt][ct], 0, 0, 0);
    }

  #pragma unroll
  for (int rt = 0; rt < RT; ++rt)
    #pragma unroll
    for (int ct = 0; ct < NCT; ++ct) {
      int col = bn + ct * 16 + m15;
      if (col < N) {
        #pragma unroll
        for (int r = 0; r < 4; ++r) {
          long row = bm + wv * (BM / 4) + rt * 16 + quad * 4 + r;
          outp[row * ldo + col] = f2b(acc[rt][ct][r]);
        }
      }
    }
}

// ======== attn-out GEMM (v @ M_b) + residual + fused LayerNorm2 epilogue ========
// out = x + v@M (fp32), y2 = LN(out) (bf16). BM=128, BN=96 (full row per block).
__global__ __launch_bounds__(256) void mfma_gemm_attn(
    const bf16* __restrict__ A, const float* __restrict__ M,
    const float* __restrict__ res, const float* __restrict__ gam, const float* __restrict__ bet,
    float* __restrict__ outp, bf16* __restrict__ y2)
{
  constexpr int KP = 136;
  __shared__ __align__(16) bf16 Bs[96 * KP];
  const int tid  = threadIdx.x;
  const long bm  = (long)blockIdx.x * 128;
  const int lane = tid & 63;
  const int wv   = tid >> 6;
  const int m15  = lane & 15;
  const int quad = lane >> 4;

  const float* Mp = M + (bm >> 16) * (CDIM * CDIM);
  for (int idx = tid; idx < 96 * 96; idx += 256) {
    int k = idx / 96, n = idx - k * 96;
    Bs[n * KP + k] = f2b(Mp[k * 96 + n]);
  }

  short8 areg[2][3];
  #pragma unroll
  for (int rt = 0; rt < 2; ++rt) {
    const bf16* ap = A + (bm + wv * 32 + rt * 16 + m15) * C3 + quad * 8;
    #pragma unroll
    for (int kk = 0; kk < 3; ++kk)
      areg[rt][kk] = *reinterpret_cast<const short8*>(ap + kk * 32);
  }

  __syncthreads();

  floatx4 acc[2][6];
  #pragma unroll
  for (int rt = 0; rt < 2; ++rt)
    #pragma unroll
    for (int ct = 0; ct < 6; ++ct)
      acc[rt][ct] = (floatx4){0.f, 0.f, 0.f, 0.f};

  #pragma unroll
  for (int kk = 0; kk < 3; ++kk)
    #pragma unroll
    for (int ct = 0; ct < 6; ++ct) {
      short8 b = *reinterpret_cast<const short8*>(&Bs[(ct * 16 + m15) * KP + kk * 32 + quad * 8]);
      #pragma unroll
      for (int rt = 0; rt < 2; ++rt)
        acc[rt][ct] = __builtin_amdgcn_mfma_f32_16x16x32_bf16(areg[rt][kk], b, acc[rt][ct], 0, 0, 0);
    }

  float gv[6], bv[6];
  #pragma unroll
  for (int ct = 0; ct < 6; ++ct) { gv[ct] = gam[ct * 16 + m15]; bv[ct] = bet[ct * 16 + m15]; }

  #pragma unroll
  for (int rt = 0; rt < 2; ++rt)
    #pragma unroll
    for (int r = 0; r < 4; ++r) {
      long row = bm + wv * 32 + rt * 16 + quad * 4 + r;
      float v[6];
      float s = 0.f, sq = 0.f;
      #pragma unroll
      for (int ct = 0; ct < 6; ++ct) {
        v[ct] = acc[rt][ct][r] + res[row * CDIM + ct * 16 + m15];
        s += v[ct]; sq += v[ct] * v[ct];
      }
      #pragma unroll
      for (int off = 8; off; off >>= 1) { s += __shfl_xor(s, off); sq += __shfl_xor(sq, off); }
      float mean = s * (1.f / 96.f);
      float var  = sq * (1.f / 96.f) - mean * mean;
      float rstd = rsqrtf(var + EPSV);
      #pragma unroll
      for (int ct = 0; ct < 6; ++ct) {
        int col = ct * 16 + m15;
        outp[row * CDIM + col] = v[ct];
        y2[row * CDIM + col] = f2b((v[ct] - mean) * rstd * gv[ct] + bv[ct]);
      }
    }
}

// ======== Spatially-tiled depthwise 3x3 conv, vectorized 8-ch I/O ========
template<int LDC, int TC, int MODE>
__global__ __launch_bounds__(256) void dwconv_tiled(
    const bf16* __restrict__ in, const float* __restrict__ kw, int kws, int cmax,
    bf16* __restrict__ out, int ldo)
{
  constexpr int VPP = TC / 8;
  __shared__ uint4 sm[VPP][18 * 18];
  const int tid = threadIdx.x;
  const int tx0 = blockIdx.x * 16;
  const int ty0 = (blockIdx.y & 15) * 16;
  const int b   = blockIdx.y >> 4;
  const int c0  = blockIdx.z * TC;
  const long bbase = (long)b * HWSZ;

  for (int f = tid; f < 18 * 18 * VPP; f += 256) {
    int pix = f / VPP;
    int v   = f - pix * VPP;
    int row = pix / 18, px = pix - row * 18;
    int y = ty0 + row - 1, x = tx0 + px - 1;
    uint4 u = make_uint4(0u, 0u, 0u, 0u);
    if ((unsigned)y < (unsigned)HH && (unsigned)x < (unsigned)WW)
      u = *reinterpret_cast<const uint4*>(in + (bbase + (long)y * WW + x) * LDC + c0 + v * 8);
    sm[v][pix] = u;
  }
  __syncthreads();

  const int x   = tid & 15;
  const int yg  = (tid >> 4) & 3;
  const int chl = tid >> 6;
  for (int cg = chl; cg < VPP; cg += 4) {
    const int cb = c0 + cg * 8;
    float wgt[9][8];
    #pragma unroll
    for (int t = 0; t < 9; ++t)
      #pragma unroll
      for (int j = 0; j < 8; ++j)
        wgt[t][j] = (cb + j < cmax) ? kw[t * kws + cb + j] : 0.f;

    #pragma unroll
    for (int yy = 0; yy < 4; ++yy) {
      const int ry = yg * 4 + yy;
      float acc[8] = {0.f, 0.f, 0.f, 0.f, 0.f, 0.f, 0.f, 0.f};
      #pragma unroll
      for (int dy = 0; dy < 3; ++dy)
        #pragma unroll
        for (int dx = 0; dx < 3; ++dx) {
          uint4 u = sm[cg][(ry + dy) * 18 + x + dx];
          const float* wt = wgt[dy * 3 + dx];
          acc[0] += lo16(u.x) * wt[0]; acc[1] += hi16(u.x) * wt[1];
          acc[2] += lo16(u.y) * wt[2]; acc[3] += hi16(u.y) * wt[3];
          acc[4] += lo16(u.z) * wt[4]; acc[5] += hi16(u.z) * wt[5];
          acc[6] += lo16(u.w) * wt[6]; acc[7] += hi16(u.w) * wt[7];
        }
      long po = bbase + (long)(ty0 + yg * 4 + yy) * WW + tx0 + x;
      bf16* op = out + po * ldo + cb;
      __align__(16) bf16 ov[8];
      if (MODE == 0) {
        #pragma unroll
        for (int j = 0; j < 8; ++j) ov[j] = f2b(acc[j]);
      } else if (MODE == 1) {
        #pragma unroll
        for (int j = 0; j < 8; ++j)
          ov[j] = f2b(0.5f * acc[j] * (1.f + erff(acc[j] * 0.70710678118654752440f)));
      } else {
        uint4 old = *reinterpret_cast<const uint4*>(op);
        ov[0] = f2b(lo16(old.x) * acc[0]); ov[1] = f2b(hi16(old.x) * acc[1]);
        ov[2] = f2b(lo16(old.y) * acc[2]); ov[3] = f2b(hi16(old.y) * acc[3]);
        ov[4] = f2b(lo16(old.z) * acc[4]); ov[5] = f2b(hi16(old.z) * acc[5]);
        ov[6] = f2b(lo16(old.w) * acc[6]); ov[7] = f2b(hi16(old.w) * acc[7]);
      }
      *reinterpret_cast<uint4*>(op) = *reinterpret_cast<const uint4*>(ov);
    }
  }
}

// ======== MFMA Gram + fused q/k L2 norms ========
__global__ __launch_bounds__(256) void gram_kernel(const bf16* __restrict__ qkv,
    float* __restrict__ G, float* __restrict__ nq, float* __restrict__ nk)
{
  constexpr int SP = 264;
  __shared__ __align__(16) char raw[2 * CH * SP * 2];   // 50688 B
  short* qs = (short*)raw;              // [48][SP]
  short* ks = qs + CH * SP;
  const int tid  = threadIdx.x;
  const int bh   = blockIdx.y;
  const int b    = bh >> 1, head = bh & 1;
  const long row0 = (long)b * HWSZ + (long)blockIdx.x * 256;
  const int lane = tid & 63;
  const int wv   = tid >> 6;
  const int m15  = lane & 15;
  const int quad = lane >> 4;

  {
    const short* src = (const short*)(qkv + (row0 + tid) * C3 + head * CH);
    #pragma unroll
    for (int v = 0; v < 6; ++v) {
      short8 q8 = *reinterpret_cast<const short8*>(src + v * 8);
      short8 k8 = *reinterpret_cast<const short8*>(src + CDIM + v * 8);
      #pragma unroll
      for (int j = 0; j < 8; ++j) {
        qs[(v * 8 + j) * SP + tid] = q8[j];
        ks[(v * 8 + j) * SP + tid] = k8[j];
      }
    }
  }
  __syncthreads();

  floatx4 acc[3][3], accq[3], acck[3];
  #pragma unroll
  for (int i = 0; i < 3; ++i) {
    accq[i] = (floatx4){0.f, 0.f, 0.f, 0.f};
    acck[i] = (floatx4){0.f, 0.f, 0.f, 0.f};
    #pragma unroll
    for (int j = 0; j < 3; ++j) acc[i][j] = (floatx4){0.f, 0.f, 0.f, 0.f};
  }

  #pragma unroll
  for (int kk = 0; kk < 2; ++kk) {
    const int s_off = wv * 64 + kk * 32 + quad * 8;
    short8 aq[3], bk[3];
    #pragma unroll
    for (int i = 0; i < 3; ++i) {
      aq[i] = *reinterpret_cast<const short8*>(&qs[(i * 16 + m15) * SP + s_off]);
      bk[i] = *reinterpret_cast<const short8*>(&ks[(i * 16 + m15) * SP + s_off]);
    }
    #pragma unroll
    for (int i = 0; i < 3; ++i) {
      accq[i] = __builtin_amdgcn_mfma_f32_16x16x32_bf16(aq[i], aq[i], accq[i], 0, 0, 0);
      acck[i] = __builtin_amdgcn_mfma_f32_16x16x32_bf16(bk[i], bk[i], acck[i], 0, 0, 0);
      #pragma unroll
      for (int j = 0; j < 3; ++j)
        acc[i][j] = __builtin_amdgcn_mfma_f32_16x16x32_bf16(aq[i], bk[j], acc[i][j], 0, 0, 0);
    }
  }

  __syncthreads();
  float* gsum = (float*)raw;            // 2304 floats
  float* nqs  = gsum + 2304;            // 48
  float* nks  = nqs + 48;               // 48
  for (int f = tid; f < 2304 + 96; f += 256) gsum[f] = 0.f;
  __syncthreads();
  const int c_lo = quad * 4;
  #pragma unroll
  for (int i = 0; i < 3; ++i)
    #pragma unroll
    for (int j = 0; j < 3; ++j)
      #pragma unroll
      for (int r = 0; r < 4; ++r)
        atomicAdd(&gsum[(i * 16 + c_lo + r) * CH + j * 16 + m15], acc[i][j][r]);
  if (m15 >= c_lo && m15 < c_lo + 4) {
    const int r = m15 - c_lo;
    #pragma unroll
    for (int i = 0; i < 3; ++i) {
      atomicAdd(&nqs[i * 16 + m15], accq[i][r]);
      atomicAdd(&nks[i * 16 + m15], acck[i][r]);
    }
  }
  __syncthreads();
  float* Gp = G + (long)bh * CH * CH;
  for (int f = tid; f < CH * CH; f += 256) atomicAdd(&Gp[f], gsum[f]);
  if (tid < CH)            atomicAdd(&nq[b * CDIM + head * CH + tid], nqs[tid]);
  else if (tid < 2 * CH)   atomicAdd(&nk[b * CDIM + head * CH + tid - CH], nks[tid - CH]);
}

// ---------------- softmax over d of G/(|q||k|)*temp ----------------
__global__ __launch_bounds__(64) void softmax_kernel(const float* __restrict__ G,
    const float* __restrict__ nq, const float* __restrict__ nk,
    const float* __restrict__ temp, float* __restrict__ attn)
{
  int r = blockIdx.x;               // 0..191 = (b*2+head)*48 + c
  int lane = threadIdx.x;
  int bh = r / CH, c = r % CH;
  int b = bh >> 1, head = bh & 1;
  float t  = temp[head];
  float qn = sqrtf(nq[b * CDIM + head * CH + c]);
  float val = 0.f, v = -INFINITY;
  if (lane < CH) {
    float kn = sqrtf(nk[b * CDIM + head * CH + lane]);
    val = G[r * CH + lane] / (qn * kn) * t;
    v = val;
  }
  float m = v;
  #pragma unroll
  for (int off = 32; off; off >>= 1) m = fmaxf(m, __shfl_xor(m, off));
  float e = (lane < CH) ? expf(val - m) : 0.f;
  float s = e;
  #pragma unroll
  for (int off = 32; off; off >>= 1) s += __shfl_xor(s, off);
  if (lane < CH) attn[r * CH + lane] = e / s;
}

// ---- M_b[k][n] = sum_cc attn[b,head(k)][cc][k%48] * aow[head(k)*48+cc][n] ----
__global__ __launch_bounds__(256) void attnmat_kernel(const float* __restrict__ attn,
    const float* __restrict__ aow, float* __restrict__ M)
{
  const int b  = blockIdx.x;
  const int k0 = blockIdx.y * 16;
  for (int idx = threadIdx.x; idx < 16 * 96; idx += 256) {
    int k = k0 + idx / 96, n = idx % 96;
    int h = k / CH, kk = k % CH;
    const float* ap = attn + ((b * 2 + h) * CH) * CH + kk;  // attn[bh][cc][kk], stride CH
    const float* wp = aow + (h * CH) * CDIM + n;            // aow[h*48+cc][n], stride CDIM
    float acc = 0.f;
    #pragma unroll
    for (int cc = 0; cc < CH; ++cc) acc += ap[cc * CH] * wp[cc * CDIM];
    M[(long)b * CDIM * CDIM + k * CDIM + n] = acc;
  }
}

extern "C" void kernel_launch(void* const* d_in, const int* in_sizes, int n_in,
                              void* d_out, int out_size, void* d_ws, size_t ws_size,
                              hipStream_t stream)
{
  const float* x          = (const float*)d_in[0];
  const float* ln1_g      = (const float*)d_in[1];
  const float* ln1_b      = (const float*)d_in[2];
  const float* ln2_g      = (const float*)d_in[3];
  const float* ln2_b      = (const float*)d_in[4];
  const float* qkv_w      = (const float*)d_in[5];
  const float* qkv_dw     = (const float*)d_in[6];
  const float* temp       = (const float*)d_in[7];
  const float* attn_out_w = (const float*)d_in[8];
  const float* ffn_in_w   = (const float*)d_in[9];
  const float* ffn_dw     = (const float*)d_in[10];
  const float* ffn_out_w  = (const float*)d_in[11];
  float* out = (float*)d_out;

  // workspace layout (peak ~177 MB)
  char* ws = (char*)d_ws;
  size_t off = 0;
  auto alloc = [&](size_t bytes) { void* p = ws + off; off += (bytes + 255) & ~(size_t)255; return p; };
  bf16*  BA  = (bf16*)alloc((size_t)NPIX * C3 * 2);    // qkv post-dwconv; later gelu(x1)/gated
  bf16*  BB  = (bf16*)alloc((size_t)NPIX * C3 * 2);    // qkv pre-dwconv; later t1/t2
  bf16*  BC  = (bf16*)alloc((size_t)NPIX * CDIM * 2);  // LN2 output (from attn epilogue)
  float* NQ  = (float*)alloc(BATCH * CDIM * 4);
  float* NK  = (float*)alloc(BATCH * CDIM * 4);
  float* G   = (float*)alloc(BATCH * HEADS * CH * CH * 4);
  float* ATT = (float*)alloc(BATCH * HEADS * CH * CH * 4);
  float* AM  = (float*)alloc(BATCH * CDIM * CDIM * 4); // fused attn matrices
  hipMemsetAsync(NQ, 0, (size_t)(768 + 768 + 36864), stream);

  // ---- attention branch ----
  // qkv = dwconv(LN1(x) @ qkv_w)
  mfma_gemm_lnA<128, 48><<<dim3(6, NPIX / 128), 256, 0, stream>>>(
      x, ln1_g, ln1_b, qkv_w, C3, C3, BB, C3);
  dwconv_tiled<C3, 48, 0><<<dim3(16, 32, 6), 256, 0, stream>>>(BB, qkv_dw, C3, C3, BA, C3);
  gram_kernel<<<dim3(256, 4), 256, 0, stream>>>(BA, G, NQ, NK);
  softmax_kernel<<<192, 64, 0, stream>>>(G, NQ, NK, temp, ATT);
  attnmat_kernel<<<dim3(2, 6), 256, 0, stream>>>(ATT, attn_out_w, AM);
  // out = x + v @ M_b;  BC = LN2(out)
  mfma_gemm_attn<<<NPIX / 128, 256, 0, stream>>>(
      BA + 2 * CDIM, AM, x, ln2_g, ln2_b, out, BC);

  // ---- FFN branch (hidden split into two 255-col halves) ----
  mfma_gemm<128, 64, 96, false, true><<<dim3(4, NPIX / 128), 256, 0, stream>>>(
      BC, CDIM, ffn_in_w, 2 * HIDN, HIDN, CDIM, BB, 256, nullptr, 0, 0);
  dwconv_tiled<256, 64, 1><<<dim3(16, 32, 4), 256, 0, stream>>>(BB, ffn_dw, 2 * HIDN, HIDN, BA, 256);
  mfma_gemm<128, 64, 96, false, true><<<dim3(4, NPIX / 128), 256, 0, stream>>>(
      BC, CDIM, ffn_in_w + HIDN, 2 * HIDN, HIDN, CDIM, BB, 256, nullptr, 0, 0);
  dwconv_tiled<256, 64, 2><<<dim3(16, 32, 4), 256, 0, stream>>>(BB, ffn_dw + HIDN, 2 * HIDN, HIDN, BA, 256);
  mfma_gemm<128, 48, 256, true, false><<<dim3(2, NPIX / 128), 256, 0, stream>>>(
      BA, 256, ffn_out_w, CDIM, CDIM, HIDN, out, CDIM, out, CDIM, 0);
}